// Round 4
// baseline (147.952 us; speedup 1.0000x reference)
//
#include <hip/hip_runtime.h>
#include <math.h>

// HarmonicCQT via f16 MFMA: out[b,t,k] = |sum_n xpad[t*512+n] * (kr[k,n]+i*ki[k,n])|
//
// R17: BARRIER-FREE main kernel. No LDS, no global_load_lds, no __syncthreads.
// Every wave is independent: A fragments (16B/lane, L1/L2-hot, 4x intra-WG
// dup absorbed by L1) and B fragments (bp is pre-packed in per-lane fragment
// order -> 1KB fully-coalesced loads) go GLOBAL->REGISTER. The compiler
// software-pipelines iteration c+1's 8 loads under iteration c's 8 MFMAs
// (counted vmcnt, no barrier drain -- the structural stall of R13-R16).
// Waves whose kernel support starts late jump straight to max(slo,gs).
// 32 frames/wave (kFBB=88, 968 WGs ~3.8 waves/SIMD for TLP). No XCD swizzle
// (R15/R16 evidence: -6us vs natural round-robin with L2-resident inputs).
//
// Path P (ws >= ~14.95MB), 3 dispatches, NO atomics:
//   1. prep_fused   : audio->f16 xp + B-fragment pack
//   2. cqt_mfma_t<true> : reg-only MFMA; epilogue = 2x16B f16 partial stores
//        to an exclusive per-(slice,fb,b,wave) region.
//   3. cqt_mag_part : sum 8/2/1 slice partials (coalesced) -> magnitude -> out
// Path A (ws >= ~10.8MB): atomic split-K (same main kernel, atomic epilogue).
// Path B (ws >= ~7.7MB): round-3 LDS-staging MFMA kernel (verified, ~224us).
// Path C: verified fp32 kernel (~370us).
//
// MFMA 16x16x32 layouts (verified rounds 3-13, absmax 4.9e-4):
//   A[m=lane&15][k=(lane>>4)*8+j], B[k=(lane>>4)*8+j][n=lane&15],
//   C/D: col=lane&15, row=(lane>>4)*4+reg.
// bp layout per 16-bin chunk (32 K-cols): 2048B = [64 lanes x 16B re][64 x 16B im]
// Partial layout: slot = ((sx*88 + fb*4+b)*4 + wave); 1024 halfs per slot,
// lane l at slot*1024 + l*16, within-lane order [tl][r][re/im], tl=0..1.

namespace {
constexpr int kSR    = 22050;
constexpr int kHop   = 512;
constexpr int kBins  = 168;
constexpr int kT     = 689;
constexpr int kB     = 4;
constexpr int kS     = 352768;
constexpr float kKScale    = 4096.0f;
constexpr float kKScaleInv = 1.0f / 4096.0f;
constexpr int kG16 = 11;              // 16-bin groups (g10 = bins 160..167)
constexpr int kFBB = 88;              // fb(22, 32 frames each) * b(4)
constexpr int kAcc = kB * kT * kBins * 2;   // path-A split-K accumulator
// path B layout
constexpr int kTPadB   = 768;
constexpr int kBinPadB = 176;
constexpr int kAccB    = kB * kTPadB * kBinPadB * 2;
}

typedef _Float16 half8 __attribute__((ext_vector_type(8)));
typedef _Float16 half2v __attribute__((ext_vector_type(2)));
typedef float floatx4 __attribute__((ext_vector_type(4)));

struct Jobs {          // path B job table
  int k0[48];
  int lo[48];
  int hi[48];
  int n;
};

struct JobsC {         // path P/A tables
  int lo16[kG16];      // support start col per 16-bin group (256-aligned)
  int cb16[kG16];      // chunk-prefix per group (bp indexing)
  int mlo[3];          // macro-group (64-bin) support start col
  int sm[24];          // per slice: macro id
  int slo[24];         // per slice: chunk range [slo,shi) rel. to mlo (even)
  int shi[24];
  int sbeg[3];         // first slice index of macro
  int scnt[3];         // slice count of macro
  int ns;
  int totch;
};

__device__ inline void atomAddF(float* p, float v) {
  __hip_atomic_fetch_add(p, v, __ATOMIC_RELAXED, __HIP_MEMORY_SCOPE_AGENT);
}

// ---- fused prep: [0,nbx) audio | [nbx,nbx+nbp) bpack | [.., +nba) zero acc ----
__global__ __launch_bounds__(256) void prep_fused(
    const float* __restrict__ x, const float* __restrict__ kr,
    const float* __restrict__ ki, _Float16* __restrict__ xp,
    _Float16* __restrict__ bp, float* __restrict__ accb,
    const int pad, const int xps, const int nmax,
    const int nbx, const int nbp, const JobsC jt) {
  int bid = blockIdx.x;
  const int tid = threadIdx.x;

  if (bid < nbx) {
    // --- padded f16 audio: 8 elements/thread, one 16B store ---
    const int octx = xps >> 3;
    const int gid = bid * 256 + tid;
    if (gid >= kB * octx) return;
    const int b = gid / octx;
    const int i = (gid - b * octx) * 8;
    const float* xb = x + (size_t)b * kS - pad;
    half8 h;
    #pragma unroll
    for (int j = 0; j < 8; ++j) {
      const int e = i + j;
      h[j] = (e >= pad && e < pad + kS) ? (_Float16)xb[e] : (_Float16)0.f;
    }
    *(half8*)&xp[(size_t)b * xps + i] = h;
    return;
  }
  bid -= nbx;

  if (bid < nbp) {
    // --- B-fragment pack: 64 threads -> one 16-bin chunk (re+im) ---
    const int chunkid = bid * 4 + (tid >> 6);
    const int lane = tid & 63;
    if (chunkid >= jt.totch) return;
    int g = 0;
    #pragma unroll
    for (int j = 1; j < kG16; ++j)
      if (chunkid >= jt.cb16[j]) g = j;
    const int c = chunkid - jt.cb16[g];
    const int mm = lane & 15;
    const int q  = lane >> 4;
    const int bin  = g * 16 + mm;
    const int col0 = jt.lo16[g] + c * 32 + q * 8;
    const bool binok = (bin < kBins);
    const float* rowr = kr + (size_t)bin * nmax;
    const float* rowi = ki + (size_t)bin * nmax;
    half8 hre, him;
    #pragma unroll
    for (int j = 0; j < 8; ++j) {
      const int col = col0 + j;
      const bool ok = binok && (col < nmax);
      hre[j] = ok ? (_Float16)(rowr[col] * kKScale) : (_Float16)0.f;
      him[j] = ok ? (_Float16)(rowi[col] * kKScale) : (_Float16)0.f;
    }
    _Float16* dst = bp + (size_t)chunkid * 1024 + lane * 8;
    *(half8*)dst = hre;
    *(half8*)(dst + 512) = him;
    return;
  }
  bid -= nbp;

  // --- zero split-K accumulator (path A only; nba=0 in path P) ---
  const int idx = (bid * 256 + tid) * 4;
  if (idx < kAcc)
    *(floatx4*)&accb[idx] = (floatx4){0.f, 0.f, 0.f, 0.f};
}

// ---- main: barrier-free, register-only MFMA, 32 frames/wave (R17) ----
// PARTIAL=true : epilogue = exclusive f16 partial stores (no atomics)
// PARTIAL=false: epilogue = guarded agent-atomic split-K
template <bool PARTIAL>
__global__ __launch_bounds__(256) void cqt_mfma_t(
    const _Float16* __restrict__ bp, const _Float16* __restrict__ xp,
    float* __restrict__ accb, _Float16* __restrict__ part,
    const int xps, const JobsC jt) {
  const int sx = blockIdx.y;
  const int fb = blockIdx.x >> 2;      // 0..21 (32 frames each)
  const int b  = blockIdx.x & 3;
  const int tid  = threadIdx.x;
  const int wave = tid >> 6;
  const int lane = tid & 63;
  const int mm = lane & 15;
  const int q  = lane >> 4;
  const int mac = jt.sm[sx];
  const int g16 = mac * 4 + wave;
  const bool gvalid = (g16 < kG16);
  const int mlo = jt.mlo[mac];
  const int gs = gvalid ? ((jt.lo16[g16] - mlo) >> 5) : 0;
  const int slo = jt.slo[sx];
  const int shi = jt.shi[sx];
  const int fbase = fb * 32;

  // per-lane A addressing: frag for chunk c, tile tl is the contiguous 16B at
  // xp[row(tl)*512 + mlo + c*32 + q*8], row(tl) = fbase + tl*16 + mm (clamped)
  const _Float16* xb = xp + (size_t)b * xps + mlo;
  int aoff[2];
  #pragma unroll
  for (int tl = 0; tl < 2; ++tl) {
    int row = fbase + tl * 16 + mm;
    if (row > kT - 1) row = kT - 1;
    aoff[tl] = row * kHop + q * 8;
  }
  // B frags are pre-packed per-lane: chunk c re at bgrp+c*1024, im at +512
  const _Float16* bgrp =
      gvalid ? (bp + (size_t)(jt.cb16[g16] - gs) * 1024 + lane * 8) : bp;

  floatx4 accr[2], acci[2];
  #pragma unroll
  for (int tl = 0; tl < 2; ++tl) {
    accr[tl] = (floatx4){0.f, 0.f, 0.f, 0.f};
    acci[tl] = (floatx4){0.f, 0.f, 0.f, 0.f};
  }

  // waves whose kernel support starts late jump straight there (no barriers
  // to honor); invalid waves skip the loop entirely.
  int c0 = slo;
  if (gvalid) { if (gs > c0) c0 = gs; } else { c0 = shi; }

  #pragma unroll 2
  for (int c = c0; c < shi; c += 2) {
    const _Float16* bs = bgrp + (size_t)c * 1024;
    const half8 Bre0 = *(const half8*)(bs);
    const half8 Bim0 = *(const half8*)(bs + 512);
    const half8 Bre1 = *(const half8*)(bs + 1024);
    const half8 Bim1 = *(const half8*)(bs + 1536);
    const _Float16* ac = xb + c * 32;
    const half8 A00 = *(const half8*)(ac + aoff[0]);
    const half8 A10 = *(const half8*)(ac + aoff[1]);
    const half8 A01 = *(const half8*)(ac + 32 + aoff[0]);
    const half8 A11 = *(const half8*)(ac + 32 + aoff[1]);
    accr[0] = __builtin_amdgcn_mfma_f32_16x16x32_f16(A00, Bre0, accr[0], 0, 0, 0);
    acci[0] = __builtin_amdgcn_mfma_f32_16x16x32_f16(A00, Bim0, acci[0], 0, 0, 0);
    accr[1] = __builtin_amdgcn_mfma_f32_16x16x32_f16(A10, Bre0, accr[1], 0, 0, 0);
    acci[1] = __builtin_amdgcn_mfma_f32_16x16x32_f16(A10, Bim0, acci[1], 0, 0, 0);
    accr[0] = __builtin_amdgcn_mfma_f32_16x16x32_f16(A01, Bre1, accr[0], 0, 0, 0);
    acci[0] = __builtin_amdgcn_mfma_f32_16x16x32_f16(A01, Bim1, acci[0], 0, 0, 0);
    accr[1] = __builtin_amdgcn_mfma_f32_16x16x32_f16(A11, Bre1, accr[1], 0, 0, 0);
    acci[1] = __builtin_amdgcn_mfma_f32_16x16x32_f16(A11, Bim1, acci[1], 0, 0, 0);
  }

  if (PARTIAL) {
    // exclusive-region f16 partial stores: 2 x 16B per lane, no RMW
    _Float16* pw = part +
        (((size_t)sx * kFBB + blockIdx.x) * 4 + wave) * 1024 + lane * 16;
    half8 p0, p1;
    #pragma unroll
    for (int r = 0; r < 4; ++r) {
      p0[r * 2]     = (_Float16)accr[0][r];
      p0[r * 2 + 1] = (_Float16)acci[0][r];
      p1[r * 2]     = (_Float16)accr[1][r];
      p1[r * 2 + 1] = (_Float16)acci[1][r];
    }
    *(half8*)pw = p0;
    *(half8*)(pw + 8) = p1;
  } else {
    // guarded agent-atomic split-K combine
    const int bin = g16 * 16 + mm;
    if (gvalid && bin < kBins) {
      #pragma unroll
      for (int tl = 0; tl < 2; ++tl) {
        const int tb = fbase + tl * 16 + q * 4;
        #pragma unroll
        for (int r = 0; r < 4; ++r) {
          const int t = tb + r;
          if (t < kT) {
            const size_t o = (((size_t)b * kT + t) * kBins + bin) * 2;
            atomAddF(&accb[o],     accr[tl][r] * kKScaleInv);
            atomAddF(&accb[o + 1], acci[tl][r] * kKScaleInv);
          }
        }
      }
    }
  }
}

// ---- path P final: sum slice partials -> magnitude -> out ----
__global__ __launch_bounds__(256) void cqt_mag_part(
    const _Float16* __restrict__ part, float* __restrict__ out,
    const JobsC jt) {
  const int fbb = blockIdx.x;          // 0..87
  const int fb = fbb >> 2;
  const int b  = fbb & 3;
  const int wave = threadIdx.x >> 6;
  const int lane = threadIdx.x & 63;
  const int g16 = blockIdx.y * 4 + wave;
  if (g16 >= kG16) return;
  const int mac = g16 >> 2;
  const int w   = g16 & 3;
  const int mm = lane & 15;
  const int q  = lane >> 4;

  float a[16];
  #pragma unroll
  for (int i = 0; i < 16; ++i) a[i] = 0.f;
  const int s0 = jt.sbeg[mac];
  const int s1 = s0 + jt.scnt[mac];
  #pragma unroll 1
  for (int s = s0; s < s1; ++s) {
    const _Float16* p = part +
        (((size_t)s * kFBB + fbb) * 4 + w) * 1024 + lane * 16;
    const half8 v0 = *(const half8*)p;
    const half8 v1 = *(const half8*)(p + 8);
    #pragma unroll
    for (int j = 0; j < 8; ++j) {
      a[j]     += (float)v0[j];
      a[8 + j] += (float)v1[j];
    }
  }
  const int k = g16 * 16 + mm;
  if (k >= kBins) return;
  #pragma unroll
  for (int tl = 0; tl < 2; ++tl) {
    #pragma unroll
    for (int r = 0; r < 4; ++r) {
      const int t = fb * 32 + tl * 16 + q * 4 + r;
      if (t < kT) {
        const float re = a[tl * 8 + r * 2];
        const float im = a[tl * 8 + r * 2 + 1];
        out[((size_t)b * kT + t) * kBins + k] =
            sqrtf(re * re + im * im) * kKScaleInv;
      }
    }
  }
}

// ---- path A final: magnitude, 4 outputs/thread ----
__global__ __launch_bounds__(256) void cqt_mag4(
    const float* __restrict__ accb, float* __restrict__ out) {
  const int gid = (blockIdx.x * 256 + threadIdx.x) * 4;
  if (gid >= kB * kT * kBins) return;
  const floatx4 v0 = *(const floatx4*)&accb[gid * 2];
  const floatx4 v1 = *(const floatx4*)&accb[gid * 2 + 4];
  floatx4 o;
  o[0] = sqrtf(v0[0] * v0[0] + v0[1] * v0[1]);
  o[1] = sqrtf(v0[2] * v0[2] + v0[3] * v0[3]);
  o[2] = sqrtf(v1[0] * v1[0] + v1[1] * v1[1]);
  o[3] = sqrtf(v1[2] * v1[2] + v1[3] * v1[3]);
  *(floatx4*)&out[gid] = o;
}

// ---- path B final: magnitude (layout-parametric) ----
__global__ __launch_bounds__(256) void cqt_mag_final(
    const float* __restrict__ accb, float* __restrict__ out,
    const int tp, const int kp) {
  int gid = blockIdx.x * 256 + threadIdx.x;
  if (gid >= kB * kT * kBins) return;
  const int k = gid % kBins;
  const int r = gid / kBins;
  const int t = r % kT;
  const int b = r / kT;
  const float2 v = ((const float2*)accb)[((size_t)b * tp + t) * kp + k];
  out[gid] = sqrtf(v.x * v.x + v.y * v.y);
}

// ================= path B: round-3 LDS-staging MFMA (verified) =============
__global__ __launch_bounds__(256) void prep_x_kernel(
    const float* __restrict__ x, _Float16* __restrict__ xp,
    const int pad, const int xps) {
  const int halfx = xps >> 1;
  int gid = blockIdx.x * 256 + threadIdx.x;
  if (gid >= kB * halfx) return;
  const int b = gid / halfx;
  const int i = (gid - b * halfx) * 2;
  float v0 = 0.f, v1 = 0.f;
  if (i     >= pad && i     < pad + kS) v0 = x[(size_t)b * kS + (i - pad)];
  if (i + 1 >= pad && i + 1 < pad + kS) v1 = x[(size_t)b * kS + (i + 1 - pad)];
  half2v h; h.x = (_Float16)v0; h.y = (_Float16)v1;
  *(half2v*)&xp[(size_t)b * xps + i] = h;
}

__global__ __launch_bounds__(256) void cqt_mfma_kernel(
    const float* __restrict__ kr, const float* __restrict__ ki,
    const _Float16* __restrict__ xp, float* __restrict__ accb,
    const int nmax, const int xps, const Jobs jt) {
  __shared__ _Float16 Bs[2][16][264];
  const int jb = blockIdx.x;
  const int k0   = jt.k0[jb];
  const int n_lo = jt.lo[jb];
  const int n_hi = jt.hi[jb];
  const int b  = blockIdx.z;
  const int fb = blockIdx.y;
  const int tid  = threadIdx.x;
  const int lane = tid & 63;
  const int wave = tid >> 6;
  const int m = lane & 15;
  const int q = lane >> 4;
  const int sbin = tid >> 4;
  const int scol = tid & 15;
  const int gbin = k0 + sbin;
  const bool binok = (gbin < kBins);
  const float* rowr = kr + (size_t)gbin * nmax;
  const float* rowi = ki + (size_t)gbin * nmax;
  const int fbase = fb * 256 + wave * 64;
  const _Float16* ax =
      xp + (size_t)b * xps + (size_t)(fbase + m) * kHop + q * 8;
  floatx4 accr[4], acci[4];
  #pragma unroll
  for (int tl = 0; tl < 4; ++tl) {
    accr[tl] = (floatx4){0.f, 0.f, 0.f, 0.f};
    acci[tl] = (floatx4){0.f, 0.f, 0.f, 0.f};
  }
  for (int n0r = n_lo; n0r < n_hi; n0r += 256) {
    __syncthreads();
    #pragma unroll
    for (int c = 0; c < 16; ++c) {
      const int col = n0r + scol + c * 16;
      const bool ok = binok && (col < nmax);
      const float vr = ok ? rowr[col] : 0.f;
      const float vi = ok ? rowi[col] : 0.f;
      Bs[0][sbin][scol + c * 16] = (_Float16)(vr * kKScale);
      Bs[1][sbin][scol + c * 16] = (_Float16)(vi * kKScale);
    }
    __syncthreads();
    const _Float16* axr = ax + n0r;
    #pragma unroll
    for (int c = 0; c < 8; ++c) {
      const int ko = c * 32 + q * 8;
      const half8 br = *(const half8*)&Bs[0][m][ko];
      const half8 bi = *(const half8*)&Bs[1][m][ko];
      #pragma unroll
      for (int tl = 0; tl < 4; ++tl) {
        const half8 a = *(const half8*)(axr + tl * 16 * kHop + c * 32);
        accr[tl] = __builtin_amdgcn_mfma_f32_16x16x32_f16(a, br, accr[tl], 0, 0, 0);
        acci[tl] = __builtin_amdgcn_mfma_f32_16x16x32_f16(a, bi, acci[tl], 0, 0, 0);
      }
    }
  }
  #pragma unroll
  for (int tl = 0; tl < 4; ++tl) {
    #pragma unroll
    for (int rr = 0; rr < 4; ++rr) {
      const int t = fbase + tl * 16 + q * 4 + rr;
      const size_t o = (((size_t)b * kTPadB + t) * kBinPadB + (k0 + m)) * 2;
      atomAddF(&accb[o],     accr[tl][rr] * kKScaleInv);
      atomAddF(&accb[o + 1], acci[tl][rr] * kKScaleInv);
    }
  }
}

// ================= path C: verified fp32 kernel (round 2) ==================
namespace fb32 {
constexpr int TT = 8;
constexpr int KG = 4;
constexpr int kTTiles  = (kT + TT - 1) / TT;
constexpr int kKGroups = kBins / KG;
constexpr int kWaves   = kB * kTTiles * kKGroups;
}

__global__ __launch_bounds__(256) void cqt_mag_kernel(
    const float* __restrict__ x,
    const float* __restrict__ kr,
    const float* __restrict__ ki,
    float* __restrict__ out,
    const int nmax, const int pad) {
  using namespace fb32;
  const int wave = (blockIdx.x << 2) + (threadIdx.x >> 6);
  const int lane = threadIdx.x & 63;
  if (wave >= kWaves) return;
  const int kg    = wave / (kB * kTTiles);
  const int rem   = wave - kg * (kB * kTTiles);
  const int b     = rem / kTTiles;
  const int ttile = rem - b * kTTiles;
  const int k0 = kg * KG;
  const int t0 = ttile * TT;
  const double Q  = 1.0 / (exp2(1.0 / 24.0) - 1.0);
  const double f0 = 32.7 * exp2((double)k0 / 24.0);
  int N = (int)ceil(Q * (double)kSR / f0) + 8;
  int full_start = nmax - N;
  if (full_start < 0) full_start = 0;
  int tbase[TT], lo[TT], t_last;
  { int t = t0 + TT - 1; if (t > kT - 1) t = kT - 1; t_last = t; }
  #pragma unroll
  for (int tt = 0; tt < TT; ++tt) {
    int t = t0 + tt; if (t > kT - 1) t = kT - 1;
    tbase[tt] = b * kS + t * kHop - pad;
    lo[tt]    = pad - t * kHop;
  }
  int head_start = pad - t_last * kHop;
  if (head_start < full_start) head_start = full_start;
  int safe = pad - t0 * kHop;
  if (safe < head_start) safe = head_start;
  int body_start = nmax - ((nmax - safe) & ~63);
  float accr[TT][KG], acci[TT][KG];
  #pragma unroll
  for (int tt = 0; tt < TT; ++tt)
    #pragma unroll
    for (int kk = 0; kk < KG; ++kk) { accr[tt][kk] = 0.f; acci[tt][kk] = 0.f; }
  for (int n = body_start - 64; n > head_start - 64; n -= 64) {
    const int nn = n + lane;
    const bool kok = (nn >= 0);
    float krv[KG], kiv[KG];
    #pragma unroll
    for (int kk = 0; kk < KG; ++kk) {
      krv[kk] = kok ? kr[(k0 + kk) * nmax + nn] : 0.f;
      kiv[kk] = kok ? ki[(k0 + kk) * nmax + nn] : 0.f;
    }
    float a[TT];
    #pragma unroll
    for (int tt = 0; tt < TT; ++tt)
      a[tt] = (nn >= lo[tt]) ? x[tbase[tt] + nn] : 0.f;
    #pragma unroll
    for (int tt = 0; tt < TT; ++tt)
      #pragma unroll
      for (int kk = 0; kk < KG; ++kk) {
        accr[tt][kk] = fmaf(a[tt], krv[kk], accr[tt][kk]);
        acci[tt][kk] = fmaf(a[tt], kiv[kk], acci[tt][kk]);
      }
  }
  for (int n = body_start; n < nmax; n += 64) {
    const int nn = n + lane;
    float krv[KG], kiv[KG];
    #pragma unroll
    for (int kk = 0; kk < KG; ++kk) {
      krv[kk] = kr[(k0 + kk) * nmax + nn];
      kiv[kk] = ki[(k0 + kk) * nmax + nn];
    }
    float a[TT];
    #pragma unroll
    for (int tt = 0; tt < TT; ++tt)
      a[tt] = x[tbase[tt] + nn];
    #pragma unroll
    for (int tt = 0; tt < TT; ++tt)
      #pragma unroll
      for (int kk = 0; kk < KG; ++kk) {
        accr[tt][kk] = fmaf(a[tt], krv[kk], accr[tt][kk]);
        acci[tt][kk] = fmaf(a[tt], kiv[kk], acci[tt][kk]);
      }
  }
  #pragma unroll
  for (int tt = 0; tt < TT; ++tt) {
    #pragma unroll
    for (int kk = 0; kk < KG; ++kk) {
      float r = accr[tt][kk];
      float i = acci[tt][kk];
      #pragma unroll
      for (int s = 32; s > 0; s >>= 1) {
        r += __shfl_xor(r, s, 64);
        i += __shfl_xor(i, s, 64);
      }
      if (lane == 0) {
        const int t = t0 + tt;
        if (t < kT)
          out[(b * kT + t) * kBins + (k0 + kk)] = sqrtf(r * r + i * i);
      }
    }
  }
}
// ============================================================================

extern "C" void kernel_launch(void* const* d_in, const int* in_sizes, int n_in,
                              void* d_out, int out_size, void* d_ws, size_t ws_size,
                              hipStream_t stream) {
  const float* x  = (const float*)d_in[0];   // [4, 1, 352768]
  const float* kr = (const float*)d_in[1];   // [168, nmax]
  const float* ki = (const float*)d_in[2];   // [168, nmax]
  float* out = (float*)d_out;                // [4, 1, 689, 168]

  const int nmax = in_sizes[1] / kBins;      // 23013 (runtime truth)
  const int pad  = nmax - kHop;

  const int kcap = ((nmax + 255) / 256) * 256;   // 23040
  const double Q = 1.0 / (exp2(1.0 / 24.0) - 1.0);

  // ---- path P/A tables ----
  JobsC jc;
  int tot = 0;
  for (int g = 0; g < kG16; ++g) {
    const double f0 = 32.7 * exp2((double)(16 * g) / 24.0);
    const int N = (int)ceil(Q * (double)kSR / f0) + 8;
    int lo = nmax - N;
    if (lo < 0) lo = 0;
    lo &= ~255;
    jc.lo16[g] = lo;
    jc.cb16[g] = tot;
    tot += (kcap - lo) / 32;
  }
  jc.totch = tot;                        // ~1980 chunks
  // ns=11 slice table (8/2/1, <=96 chunks)
  int ns = 0;
  for (int m = 0; m < 3; ++m) {
    jc.mlo[m] = jc.lo16[4 * m];
    jc.sbeg[m] = ns;
    const int C = (kcap - jc.mlo[m]) / 32;       // 720 / 120 / 24
    const int nsl = (C + 95) / 96;               // 8 / 2 / 1
    const int len = ((C + nsl - 1) / nsl + 1) & ~1;
    for (int s = 0; s < nsl && ns < 24; ++s) {
      const int lo = s * len;
      if (lo >= C) break;
      int hi = lo + len;
      if (hi > C) hi = C;
      jc.sm[ns] = m; jc.slo[ns] = lo; jc.shi[ns] = hi;
      ++ns;
    }
    jc.scnt[m] = ns - jc.sbeg[m];
  }
  jc.ns = ns;                            // 11 expected

  // ---- shared ws pieces ----
  const int xpsA = (kT - 1) * kHop + kcap + 256;           // 375,552 (%8==0)
  const size_t xpA_bytes = (size_t)kB * xpsA * sizeof(_Float16);
  const size_t bpA_bytes = (size_t)tot * 2048;

  // path P layout: xp | part(f16) | bp
  const size_t partP_off   = (xpA_bytes + 511) & ~(size_t)511;
  const size_t partP_bytes = (size_t)ns * kFBB * 4 * 1024 * sizeof(_Float16);
  const size_t bpP_off     = (partP_off + partP_bytes + 511) & ~(size_t)511;
  const size_t ws_P = bpP_off + bpA_bytes;                 // ~14.95 MB

  // path A layout: xp | acc(f32) | bp
  const size_t accA_off  = (xpA_bytes + 511) & ~(size_t)511;
  const size_t accA_bytes = (size_t)kAcc * sizeof(float);
  const size_t bpA_off   = (accA_off + accA_bytes + 511) & ~(size_t)511;
  const size_t ws_A = bpA_off + bpA_bytes;                 // ~10.8 MB

  // path B layout
  const int xpsB = (kTPadB - 1) * kHop + kcap + 256;
  const size_t xpB_bytes = (size_t)kB * xpsB * sizeof(_Float16);
  const size_t accB_off  = (xpB_bytes + 511) & ~(size_t)511;
  const size_t accB_bytes = (size_t)kAccB * sizeof(float);
  const size_t ws_B = accB_off + accB_bytes;

  const int nbx = (kB * (xpsA / 8) + 255) / 256;   // audio blocks (8 el/thr)
  const int nbp = (tot + 3) / 4;                   // bpack blocks (4 chunks ea)

  if (ws_size >= ws_P) {
    // ---- path P: partial-store split-K, no atomics ----
    _Float16* xp   = (_Float16*)d_ws;
    _Float16* part = (_Float16*)((char*)d_ws + partP_off);
    _Float16* bp   = (_Float16*)((char*)d_ws + bpP_off);

    prep_fused<<<nbx + nbp, 256, 0, stream>>>(
        x, kr, ki, xp, bp, (float*)part /*unused*/, pad, xpsA, nmax,
        nbx, nbp, jc);
    {
      dim3 grid(kFBB, ns);
      cqt_mfma_t<true><<<grid, 256, 0, stream>>>(
          bp, xp, nullptr, part, xpsA, jc);
    }
    {
      dim3 grid(kFBB, 3);    // 11 g16 waves per (fb,b) in 3 4-wave WGs
      cqt_mag_part<<<grid, 256, 0, stream>>>(part, out, jc);
    }
    return;
  }

  if (ws_size >= ws_A) {
    // ---- path A: atomic split-K ----
    _Float16* xp = (_Float16*)d_ws;
    float* accb  = (float*)((char*)d_ws + accA_off);
    _Float16* bp = (_Float16*)((char*)d_ws + bpA_off);

    const int nba = (kAcc / 4 + 255) / 256;
    prep_fused<<<nbx + nbp + nba, 256, 0, stream>>>(
        x, kr, ki, xp, bp, accb, pad, xpsA, nmax, nbx, nbp, jc);
    {
      dim3 grid(kFBB, ns);
      cqt_mfma_t<false><<<grid, 256, 0, stream>>>(
          bp, xp, accb, nullptr, xpsA, jc);
    }
    {
      const int total = kB * kT * kBins;
      cqt_mag4<<<(total / 4 + 255) / 256, 256, 0, stream>>>(accb, out);
    }
    return;
  }

  if (ws_size >= ws_B) {
    // ---- path B (round-3, verified ~224us) ----
    _Float16* xp = (_Float16*)d_ws;
    float* accb  = (float*)((char*)d_ws + accB_off);
    Jobs jt;
    int nj = 0;
    for (int g = 0; g < 11; ++g) {
      const int gk0 = 16 * g;
      const double f0 = 32.7 * exp2((double)gk0 / 24.0);
      const int N = (int)ceil(Q * (double)kSR / f0) + 8;
      int lo = nmax - N;
      if (lo < 0) lo = 0;
      lo = (lo / 2048) * 2048;
      for (int s = lo; s < kcap && nj < 48; s += 2048) {
        jt.k0[nj] = gk0;
        jt.lo[nj] = s;
        jt.hi[nj] = (s + 2048 < kcap) ? s + 2048 : kcap;
        ++nj;
      }
    }
    jt.n = nj;
    hipMemsetAsync(accb, 0, accB_bytes, stream);
    {
      const int total = kB * (xpsB / 2);
      prep_x_kernel<<<(total + 255) / 256, 256, 0, stream>>>(x, xp, pad, xpsB);
    }
    {
      dim3 grid(nj, kTPadB / 256, kB);
      cqt_mfma_kernel<<<grid, 256, 0, stream>>>(kr, ki, xp, accb, nmax, xpsB, jt);
    }
    {
      const int total = kB * kT * kBins;
      cqt_mag_final<<<(total + 255) / 256, 256, 0, stream>>>(
          accb, out, kTPadB, kBinPadB);
    }
    return;
  }

  // ---- path C: fp32 fallback ----
  {
    const int blocks = fb32::kWaves / 4;
    cqt_mag_kernel<<<blocks, 256, 0, stream>>>(x, kr, ki, out, nmax, pad);
  }
}

// Round 5
// 145.220 us; speedup vs baseline: 1.0188x; 1.0188x over previous
//
#include <hip/hip_runtime.h>
#include <math.h>

// HarmonicCQT via f16 MFMA: out[b,t,k] = |sum_n xpad[t*512+n] * (kr[k,n]+i*ki[k,n])|
//
// R18: balanced wave-job table + manual register double-buffering.
// R17's counters (MfmaUtil 6.3%, VALUBusy 7.8%, Occ 19%, VGPR 36) showed the
// barrier-free loop was latency-bound from (a) no compiler pipelining and
// (b) wave imbalance (fixed 4-bin-group waves idle where support is short).
// Fix: (1) flatten to per-WAVE jobs (g16 group, ~60-chunk segment, fbb) --
// 37 rows x 88 fbb = 3256 jobs, 814 WGs, every wave fully busy; (2) two
// named fragment sets U/V ping-pong: LD(V,c+2); MM(U); LD(U,c+4); MM(V) --
// one full step of load latency hidden by program order (VGPR ~100).
// Partials shrink to nrows*88*2KB = 6.7MB -> ws_P ~13.8MB (safer).
//
// Path P, 3 dispatches, NO atomics:
//   1. prep_fused   : audio->f16 xp + B-fragment pack
//   2. cqt_mfma_t<true> : reg-only pipelined MFMA; epilogue = 2x16B f16
//        partial stores to the exclusive per-job slot.
//   3. cqt_mag_part : sum jcnt[g] row partials -> magnitude -> out
// Path A: atomic split-K (same main kernel, atomic epilogue).
// Path B: round-3 LDS-staging MFMA kernel (verified, ~224us).
// Path C: verified fp32 kernel (~370us).
//
// MFMA 16x16x32 layouts (verified rounds 3-13, absmax 4.9e-4):
//   A[m=lane&15][k=(lane>>4)*8+j], B[k=(lane>>4)*8+j][n=lane&15],
//   C/D: col=lane&15, row=(lane>>4)*4+reg.
// bp layout per 16-bin chunk (32 K-cols): 2048B = [64 lanes x 16B re][64 x 16B im]
// Partial layout: slot = job id = row*88 + fbb; 1024 halfs per slot,
// lane l at slot*1024 + l*16, within-lane order [tl][r][re/im], tl=0..1.

namespace {
constexpr int kSR    = 22050;
constexpr int kHop   = 512;
constexpr int kBins  = 168;
constexpr int kT     = 689;
constexpr int kB     = 4;
constexpr int kS     = 352768;
constexpr float kKScale    = 4096.0f;
constexpr float kKScaleInv = 1.0f / 4096.0f;
constexpr int kG16 = 11;              // 16-bin groups (g10 = bins 160..167)
constexpr int kFBB = 88;              // fb(22, 32 frames each) * b(4)
constexpr int kAcc = kB * kT * kBins * 2;   // path-A split-K accumulator
// path B layout
constexpr int kTPadB   = 768;
constexpr int kBinPadB = 176;
constexpr int kAccB    = kB * kTPadB * kBinPadB * 2;
}

typedef _Float16 half8 __attribute__((ext_vector_type(8)));
typedef _Float16 half2v __attribute__((ext_vector_type(2)));
typedef float floatx4 __attribute__((ext_vector_type(4)));

struct Jobs {          // path B job table
  int k0[48];
  int lo[48];
  int hi[48];
  int n;
};

struct JobsC {         // path P/A tables
  int lo16[kG16];      // support start col per 16-bin group (256-aligned)
  int cb16[kG16];      // chunk-prefix per group (bp indexing)
  int rg[48];          // per row: bin-group
  int rlo[48];         // per row: chunk range [rlo,rhi) rel. to lo16[g], even
  int rhi[48];
  int jbeg[kG16];      // first row of group g
  int jcnt[kG16];      // row count of group g
  int nrows;
  int totch;
};

__device__ inline void atomAddF(float* p, float v) {
  __hip_atomic_fetch_add(p, v, __ATOMIC_RELAXED, __HIP_MEMORY_SCOPE_AGENT);
}

// ---- fused prep: [0,nbx) audio | [nbx,nbx+nbp) bpack | [.., +nba) zero acc ----
__global__ __launch_bounds__(256) void prep_fused(
    const float* __restrict__ x, const float* __restrict__ kr,
    const float* __restrict__ ki, _Float16* __restrict__ xp,
    _Float16* __restrict__ bp, float* __restrict__ accb,
    const int pad, const int xps, const int nmax,
    const int nbx, const int nbp, const JobsC jt) {
  int bid = blockIdx.x;
  const int tid = threadIdx.x;

  if (bid < nbx) {
    // --- padded f16 audio: 8 elements/thread, one 16B store ---
    const int octx = xps >> 3;
    const int gid = bid * 256 + tid;
    if (gid >= kB * octx) return;
    const int b = gid / octx;
    const int i = (gid - b * octx) * 8;
    const float* xb = x + (size_t)b * kS - pad;
    half8 h;
    #pragma unroll
    for (int j = 0; j < 8; ++j) {
      const int e = i + j;
      h[j] = (e >= pad && e < pad + kS) ? (_Float16)xb[e] : (_Float16)0.f;
    }
    *(half8*)&xp[(size_t)b * xps + i] = h;
    return;
  }
  bid -= nbx;

  if (bid < nbp) {
    // --- B-fragment pack: 64 threads -> one 16-bin chunk (re+im) ---
    const int chunkid = bid * 4 + (tid >> 6);
    const int lane = tid & 63;
    if (chunkid >= jt.totch) return;
    int g = 0;
    #pragma unroll
    for (int j = 1; j < kG16; ++j)
      if (chunkid >= jt.cb16[j]) g = j;
    const int c = chunkid - jt.cb16[g];
    const int mm = lane & 15;
    const int q  = lane >> 4;
    const int bin  = g * 16 + mm;
    const int col0 = jt.lo16[g] + c * 32 + q * 8;
    const bool binok = (bin < kBins);
    const float* rowr = kr + (size_t)bin * nmax;
    const float* rowi = ki + (size_t)bin * nmax;
    half8 hre, him;
    #pragma unroll
    for (int j = 0; j < 8; ++j) {
      const int col = col0 + j;
      const bool ok = binok && (col < nmax);
      hre[j] = ok ? (_Float16)(rowr[col] * kKScale) : (_Float16)0.f;
      him[j] = ok ? (_Float16)(rowi[col] * kKScale) : (_Float16)0.f;
    }
    _Float16* dst = bp + (size_t)chunkid * 1024 + lane * 8;
    *(half8*)dst = hre;
    *(half8*)(dst + 512) = him;
    return;
  }
  bid -= nbp;

  // --- zero split-K accumulator (path A only; nba=0 in path P) ---
  const int idx = (bid * 256 + tid) * 4;
  if (idx < kAcc)
    *(floatx4*)&accb[idx] = (floatx4){0.f, 0.f, 0.f, 0.f};
}

// ---- main: barrier-free, reg-double-buffered MFMA, one job per wave (R18) --
// PARTIAL=true : epilogue = exclusive f16 partial stores (no atomics)
// PARTIAL=false: epilogue = guarded agent-atomic split-K
#define LD(S, c)                                                       \
  { const _Float16* bs_ = bgrp + (size_t)(c) * 1024;                   \
    S##B0 = *(const half8*)(bs_);                                      \
    S##B1 = *(const half8*)(bs_ + 512);                                \
    S##B2 = *(const half8*)(bs_ + 1024);                               \
    S##B3 = *(const half8*)(bs_ + 1536);                               \
    const _Float16* ac_ = xb + (size_t)(c) * 32;                       \
    S##A0 = *(const half8*)(ac_ + aoff0);                              \
    S##A1 = *(const half8*)(ac_ + aoff1);                              \
    S##A2 = *(const half8*)(ac_ + 32 + aoff0);                         \
    S##A3 = *(const half8*)(ac_ + 32 + aoff1); }

#define MM(S)                                                                     \
  { accr0 = __builtin_amdgcn_mfma_f32_16x16x32_f16(S##A0, S##B0, accr0, 0, 0, 0); \
    acci0 = __builtin_amdgcn_mfma_f32_16x16x32_f16(S##A0, S##B1, acci0, 0, 0, 0); \
    accr1 = __builtin_amdgcn_mfma_f32_16x16x32_f16(S##A1, S##B0, accr1, 0, 0, 0); \
    acci1 = __builtin_amdgcn_mfma_f32_16x16x32_f16(S##A1, S##B1, acci1, 0, 0, 0); \
    accr0 = __builtin_amdgcn_mfma_f32_16x16x32_f16(S##A2, S##B2, accr0, 0, 0, 0); \
    acci0 = __builtin_amdgcn_mfma_f32_16x16x32_f16(S##A2, S##B3, acci0, 0, 0, 0); \
    accr1 = __builtin_amdgcn_mfma_f32_16x16x32_f16(S##A3, S##B2, accr1, 0, 0, 0); \
    acci1 = __builtin_amdgcn_mfma_f32_16x16x32_f16(S##A3, S##B3, acci1, 0, 0, 0); }

template <bool PARTIAL>
__global__ __launch_bounds__(256) void cqt_mfma_t(
    const _Float16* __restrict__ bp, const _Float16* __restrict__ xp,
    float* __restrict__ accb, _Float16* __restrict__ part,
    const int xps, const int nw, const JobsC jt) {
  const int wave = threadIdx.x >> 6;
  const int lane = threadIdx.x & 63;
  const int id = blockIdx.x * 4 + wave;
  if (id >= nw) return;
  const int row = id / kFBB;
  const int fbb = id - row * kFBB;
  const int fb = fbb >> 2;             // 0..21 (32 frames each)
  const int b  = fbb & 3;
  const int mm = lane & 15;
  const int q  = lane >> 4;
  const int g   = jt.rg[row];
  const int clo = jt.rlo[row];
  const int chi = jt.rhi[row];
  const int fbase = fb * 32;

  // per-lane A addressing: frag for chunk c, tile tl is the contiguous 16B at
  // xp[row(tl)*512 + lo16[g] + c*32 + q*8], row(tl) = fbase+tl*16+mm (clamped)
  const _Float16* xb = xp + (size_t)b * xps + jt.lo16[g];
  int aoff0, aoff1;
  {
    int r0 = fbase + mm;        if (r0 > kT - 1) r0 = kT - 1;
    int r1 = fbase + 16 + mm;   if (r1 > kT - 1) r1 = kT - 1;
    aoff0 = r0 * kHop + q * 8;
    aoff1 = r1 * kHop + q * 8;
  }
  // B frags are pre-packed per-lane: chunk c re at bgrp+c*1024, im at +512
  const _Float16* bgrp = bp + (size_t)jt.cb16[g] * 1024 + lane * 8;

  floatx4 accr0 = (floatx4){0.f, 0.f, 0.f, 0.f};
  floatx4 acci0 = (floatx4){0.f, 0.f, 0.f, 0.f};
  floatx4 accr1 = (floatx4){0.f, 0.f, 0.f, 0.f};
  floatx4 acci1 = (floatx4){0.f, 0.f, 0.f, 0.f};

  half8 UA0, UA1, UA2, UA3, UB0, UB1, UB2, UB3;
  half8 VA0, VA1, VA2, VA3, VB0, VB1, VB2, VB3;

  // software pipeline: LD(V,c+2); MM(U); LD(U,c+4); MM(V)
  // (row length chi-clo is always even and >= 2)
  int c = clo;
  LD(U, c);
  #pragma unroll 1
  for (; c + 4 < chi; c += 4) {
    LD(V, c + 2);
    MM(U);
    LD(U, c + 4);
    MM(V);
  }
  if (c + 2 < chi) {     // two 2-chunk steps remain
    LD(V, c + 2);
    MM(U);
    MM(V);
  } else {               // one step remains
    MM(U);
  }

  if (PARTIAL) {
    // exclusive-region f16 partial stores: 2 x 16B per lane, no RMW
    _Float16* pw = part + (size_t)id * 1024 + lane * 16;
    half8 p0, p1;
    #pragma unroll
    for (int r = 0; r < 4; ++r) {
      p0[r * 2]     = (_Float16)accr0[r];
      p0[r * 2 + 1] = (_Float16)acci0[r];
      p1[r * 2]     = (_Float16)accr1[r];
      p1[r * 2 + 1] = (_Float16)acci1[r];
    }
    *(half8*)pw = p0;
    *(half8*)(pw + 8) = p1;
  } else {
    // guarded agent-atomic split-K combine
    const int bin = g * 16 + mm;
    if (bin < kBins) {
      #pragma unroll
      for (int r = 0; r < 4; ++r) {
        const int t0 = fbase + q * 4 + r;
        if (t0 < kT) {
          const size_t o = (((size_t)b * kT + t0) * kBins + bin) * 2;
          atomAddF(&accb[o],     accr0[r] * kKScaleInv);
          atomAddF(&accb[o + 1], acci0[r] * kKScaleInv);
        }
        const int t1 = fbase + 16 + q * 4 + r;
        if (t1 < kT) {
          const size_t o = (((size_t)b * kT + t1) * kBins + bin) * 2;
          atomAddF(&accb[o],     accr1[r] * kKScaleInv);
          atomAddF(&accb[o + 1], acci1[r] * kKScaleInv);
        }
      }
    }
  }
}
#undef LD
#undef MM

// ---- path P final: sum row partials -> magnitude -> out ----
__global__ __launch_bounds__(256) void cqt_mag_part(
    const _Float16* __restrict__ part, float* __restrict__ out,
    const JobsC jt) {
  const int fbb = blockIdx.x;          // 0..87
  const int fb = fbb >> 2;
  const int b  = fbb & 3;
  const int wave = threadIdx.x >> 6;
  const int lane = threadIdx.x & 63;
  const int g16 = blockIdx.y * 4 + wave;
  if (g16 >= kG16) return;
  const int mm = lane & 15;
  const int q  = lane >> 4;

  float a[16];
  #pragma unroll
  for (int i = 0; i < 16; ++i) a[i] = 0.f;
  const int s0 = jt.jbeg[g16];
  const int s1 = s0 + jt.jcnt[g16];
  #pragma unroll 1
  for (int s = s0; s < s1; ++s) {
    const _Float16* p = part + ((size_t)s * kFBB + fbb) * 1024 + lane * 16;
    const half8 v0 = *(const half8*)p;
    const half8 v1 = *(const half8*)(p + 8);
    #pragma unroll
    for (int j = 0; j < 8; ++j) {
      a[j]     += (float)v0[j];
      a[8 + j] += (float)v1[j];
    }
  }
  const int k = g16 * 16 + mm;
  if (k >= kBins) return;
  #pragma unroll
  for (int tl = 0; tl < 2; ++tl) {
    #pragma unroll
    for (int r = 0; r < 4; ++r) {
      const int t = fb * 32 + tl * 16 + q * 4 + r;
      if (t < kT) {
        const float re = a[tl * 8 + r * 2];
        const float im = a[tl * 8 + r * 2 + 1];
        out[((size_t)b * kT + t) * kBins + k] =
            sqrtf(re * re + im * im) * kKScaleInv;
      }
    }
  }
}

// ---- path A final: magnitude, 4 outputs/thread ----
__global__ __launch_bounds__(256) void cqt_mag4(
    const float* __restrict__ accb, float* __restrict__ out) {
  const int gid = (blockIdx.x * 256 + threadIdx.x) * 4;
  if (gid >= kB * kT * kBins) return;
  const floatx4 v0 = *(const floatx4*)&accb[gid * 2];
  const floatx4 v1 = *(const floatx4*)&accb[gid * 2 + 4];
  floatx4 o;
  o[0] = sqrtf(v0[0] * v0[0] + v0[1] * v0[1]);
  o[1] = sqrtf(v0[2] * v0[2] + v0[3] * v0[3]);
  o[2] = sqrtf(v1[0] * v1[0] + v1[1] * v1[1]);
  o[3] = sqrtf(v1[2] * v1[2] + v1[3] * v1[3]);
  *(floatx4*)&out[gid] = o;
}

// ---- path B final: magnitude (layout-parametric) ----
__global__ __launch_bounds__(256) void cqt_mag_final(
    const float* __restrict__ accb, float* __restrict__ out,
    const int tp, const int kp) {
  int gid = blockIdx.x * 256 + threadIdx.x;
  if (gid >= kB * kT * kBins) return;
  const int k = gid % kBins;
  const int r = gid / kBins;
  const int t = r % kT;
  const int b = r / kT;
  const float2 v = ((const float2*)accb)[((size_t)b * tp + t) * kp + k];
  out[gid] = sqrtf(v.x * v.x + v.y * v.y);
}

// ================= path B: round-3 LDS-staging MFMA (verified) =============
__global__ __launch_bounds__(256) void prep_x_kernel(
    const float* __restrict__ x, _Float16* __restrict__ xp,
    const int pad, const int xps) {
  const int halfx = xps >> 1;
  int gid = blockIdx.x * 256 + threadIdx.x;
  if (gid >= kB * halfx) return;
  const int b = gid / halfx;
  const int i = (gid - b * halfx) * 2;
  float v0 = 0.f, v1 = 0.f;
  if (i     >= pad && i     < pad + kS) v0 = x[(size_t)b * kS + (i - pad)];
  if (i + 1 >= pad && i + 1 < pad + kS) v1 = x[(size_t)b * kS + (i + 1 - pad)];
  half2v h; h.x = (_Float16)v0; h.y = (_Float16)v1;
  *(half2v*)&xp[(size_t)b * xps + i] = h;
}

__global__ __launch_bounds__(256) void cqt_mfma_kernel(
    const float* __restrict__ kr, const float* __restrict__ ki,
    const _Float16* __restrict__ xp, float* __restrict__ accb,
    const int nmax, const int xps, const Jobs jt) {
  __shared__ _Float16 Bs[2][16][264];
  const int jb = blockIdx.x;
  const int k0   = jt.k0[jb];
  const int n_lo = jt.lo[jb];
  const int n_hi = jt.hi[jb];
  const int b  = blockIdx.z;
  const int fb = blockIdx.y;
  const int tid  = threadIdx.x;
  const int lane = tid & 63;
  const int wave = tid >> 6;
  const int m = lane & 15;
  const int q = lane >> 4;
  const int sbin = tid >> 4;
  const int scol = tid & 15;
  const int gbin = k0 + sbin;
  const bool binok = (gbin < kBins);
  const float* rowr = kr + (size_t)gbin * nmax;
  const float* rowi = ki + (size_t)gbin * nmax;
  const int fbase = fb * 256 + wave * 64;
  const _Float16* ax =
      xp + (size_t)b * xps + (size_t)(fbase + m) * kHop + q * 8;
  floatx4 accr[4], acci[4];
  #pragma unroll
  for (int tl = 0; tl < 4; ++tl) {
    accr[tl] = (floatx4){0.f, 0.f, 0.f, 0.f};
    acci[tl] = (floatx4){0.f, 0.f, 0.f, 0.f};
  }
  for (int n0r = n_lo; n0r < n_hi; n0r += 256) {
    __syncthreads();
    #pragma unroll
    for (int c = 0; c < 16; ++c) {
      const int col = n0r + scol + c * 16;
      const bool ok = binok && (col < nmax);
      const float vr = ok ? rowr[col] : 0.f;
      const float vi = ok ? rowi[col] : 0.f;
      Bs[0][sbin][scol + c * 16] = (_Float16)(vr * kKScale);
      Bs[1][sbin][scol + c * 16] = (_Float16)(vi * kKScale);
    }
    __syncthreads();
    const _Float16* axr = ax + n0r;
    #pragma unroll
    for (int c = 0; c < 8; ++c) {
      const int ko = c * 32 + q * 8;
      const half8 br = *(const half8*)&Bs[0][m][ko];
      const half8 bi = *(const half8*)&Bs[1][m][ko];
      #pragma unroll
      for (int tl = 0; tl < 4; ++tl) {
        const half8 a = *(const half8*)(axr + tl * 16 * kHop + c * 32);
        accr[tl] = __builtin_amdgcn_mfma_f32_16x16x32_f16(a, br, accr[tl], 0, 0, 0);
        acci[tl] = __builtin_amdgcn_mfma_f32_16x16x32_f16(a, bi, acci[tl], 0, 0, 0);
      }
    }
  }
  #pragma unroll
  for (int tl = 0; tl < 4; ++tl) {
    #pragma unroll
    for (int rr = 0; rr < 4; ++rr) {
      const int t = fbase + tl * 16 + q * 4 + rr;
      const size_t o = (((size_t)b * kTPadB + t) * kBinPadB + (k0 + m)) * 2;
      atomAddF(&accb[o],     accr[tl][rr] * kKScaleInv);
      atomAddF(&accb[o + 1], acci[tl][rr] * kKScaleInv);
    }
  }
}

// ================= path C: verified fp32 kernel (round 2) ==================
namespace fb32 {
constexpr int TT = 8;
constexpr int KG = 4;
constexpr int kTTiles  = (kT + TT - 1) / TT;
constexpr int kKGroups = kBins / KG;
constexpr int kWaves   = kB * kTTiles * kKGroups;
}

__global__ __launch_bounds__(256) void cqt_mag_kernel(
    const float* __restrict__ x,
    const float* __restrict__ kr,
    const float* __restrict__ ki,
    float* __restrict__ out,
    const int nmax, const int pad) {
  using namespace fb32;
  const int wave = (blockIdx.x << 2) + (threadIdx.x >> 6);
  const int lane = threadIdx.x & 63;
  if (wave >= kWaves) return;
  const int kg    = wave / (kB * kTTiles);
  const int rem   = wave - kg * (kB * kTTiles);
  const int b     = rem / kTTiles;
  const int ttile = rem - b * kTTiles;
  const int k0 = kg * KG;
  const int t0 = ttile * TT;
  const double Q  = 1.0 / (exp2(1.0 / 24.0) - 1.0);
  const double f0 = 32.7 * exp2((double)k0 / 24.0);
  int N = (int)ceil(Q * (double)kSR / f0) + 8;
  int full_start = nmax - N;
  if (full_start < 0) full_start = 0;
  int tbase[TT], lo[TT], t_last;
  { int t = t0 + TT - 1; if (t > kT - 1) t = kT - 1; t_last = t; }
  #pragma unroll
  for (int tt = 0; tt < TT; ++tt) {
    int t = t0 + tt; if (t > kT - 1) t = kT - 1;
    tbase[tt] = b * kS + t * kHop - pad;
    lo[tt]    = pad - t * kHop;
  }
  int head_start = pad - t_last * kHop;
  if (head_start < full_start) head_start = full_start;
  int safe = pad - t0 * kHop;
  if (safe < head_start) safe = head_start;
  int body_start = nmax - ((nmax - safe) & ~63);
  float accr[TT][KG], acci[TT][KG];
  #pragma unroll
  for (int tt = 0; tt < TT; ++tt)
    #pragma unroll
    for (int kk = 0; kk < KG; ++kk) { accr[tt][kk] = 0.f; acci[tt][kk] = 0.f; }
  for (int n = body_start - 64; n > head_start - 64; n -= 64) {
    const int nn = n + lane;
    const bool kok = (nn >= 0);
    float krv[KG], kiv[KG];
    #pragma unroll
    for (int kk = 0; kk < KG; ++kk) {
      krv[kk] = kok ? kr[(k0 + kk) * nmax + nn] : 0.f;
      kiv[kk] = kok ? ki[(k0 + kk) * nmax + nn] : 0.f;
    }
    float a[TT];
    #pragma unroll
    for (int tt = 0; tt < TT; ++tt)
      a[tt] = (nn >= lo[tt]) ? x[tbase[tt] + nn] : 0.f;
    #pragma unroll
    for (int tt = 0; tt < TT; ++tt)
      #pragma unroll
      for (int kk = 0; kk < KG; ++kk) {
        accr[tt][kk] = fmaf(a[tt], krv[kk], accr[tt][kk]);
        acci[tt][kk] = fmaf(a[tt], kiv[kk], acci[tt][kk]);
      }
  }
  for (int n = body_start; n < nmax; n += 64) {
    const int nn = n + lane;
    float krv[KG], kiv[KG];
    #pragma unroll
    for (int kk = 0; kk < KG; ++kk) {
      krv[kk] = kr[(k0 + kk) * nmax + nn];
      kiv[kk] = ki[(k0 + kk) * nmax + nn];
    }
    float a[TT];
    #pragma unroll
    for (int tt = 0; tt < TT; ++tt)
      a[tt] = x[tbase[tt] + nn];
    #pragma unroll
    for (int tt = 0; tt < TT; ++tt)
      #pragma unroll
      for (int kk = 0; kk < KG; ++kk) {
        accr[tt][kk] = fmaf(a[tt], krv[kk], accr[tt][kk]);
        acci[tt][kk] = fmaf(a[tt], kiv[kk], acci[tt][kk]);
      }
  }
  #pragma unroll
  for (int tt = 0; tt < TT; ++tt) {
    #pragma unroll
    for (int kk = 0; kk < KG; ++kk) {
      float r = accr[tt][kk];
      float i = acci[tt][kk];
      #pragma unroll
      for (int s = 32; s > 0; s >>= 1) {
        r += __shfl_xor(r, s, 64);
        i += __shfl_xor(i, s, 64);
      }
      if (lane == 0) {
        const int t = t0 + tt;
        if (t < kT)
          out[(b * kT + t) * kBins + (k0 + kk)] = sqrtf(r * r + i * i);
      }
    }
  }
}
// ============================================================================

extern "C" void kernel_launch(void* const* d_in, const int* in_sizes, int n_in,
                              void* d_out, int out_size, void* d_ws, size_t ws_size,
                              hipStream_t stream) {
  const float* x  = (const float*)d_in[0];   // [4, 1, 352768]
  const float* kr = (const float*)d_in[1];   // [168, nmax]
  const float* ki = (const float*)d_in[2];   // [168, nmax]
  float* out = (float*)d_out;                // [4, 1, 689, 168]

  const int nmax = in_sizes[1] / kBins;      // 23013 (runtime truth)
  const int pad  = nmax - kHop;

  const int kcap = ((nmax + 255) / 256) * 256;   // 23040
  const double Q = 1.0 / (exp2(1.0 / 24.0) - 1.0);

  // ---- path P/A tables ----
  JobsC jc;
  int tot = 0;
  for (int g = 0; g < kG16; ++g) {
    const double f0 = 32.7 * exp2((double)(16 * g) / 24.0);
    const int N = (int)ceil(Q * (double)kSR / f0) + 8;
    int lo = nmax - N;
    if (lo < 0) lo = 0;
    lo &= ~255;
    jc.lo16[g] = lo;
    jc.cb16[g] = tot;
    tot += (kcap - lo) / 32;
  }
  jc.totch = tot;                        // ~1984 chunks
  // balanced wave-job rows: per group, segments of ~60 chunks (even length)
  int nrows = 0;
  for (int g = 0; g < kG16; ++g) {
    const int S = (kcap - jc.lo16[g]) / 32;      // support chunks (even)
    int nr = (S + 63) / 64;
    int len = ((S + nr - 1) / nr + 1) & ~1;      // even, balanced
    jc.jbeg[g] = nrows;
    for (int s = 0; s < nr && nrows < 48; ++s) {
      const int lo = s * len;
      if (lo >= S) break;
      int hi = lo + len;
      if (hi > S) hi = S;
      jc.rg[nrows] = g; jc.rlo[nrows] = lo; jc.rhi[nrows] = hi;
      ++nrows;
    }
    jc.jcnt[g] = nrows - jc.jbeg[g];
  }
  jc.nrows = nrows;                      // ~37 expected
  const int NW = nrows * kFBB;           // ~3256 wave-jobs

  // ---- shared ws pieces ----
  const int xpsA = (kT - 1) * kHop + kcap + 256;           // 375,552 (%8==0)
  const size_t xpA_bytes = (size_t)kB * xpsA * sizeof(_Float16);
  const size_t bpA_bytes = (size_t)tot * 2048;

  // path P layout: xp | part(f16) | bp
  const size_t partP_off   = (xpA_bytes + 511) & ~(size_t)511;
  const size_t partP_bytes = (size_t)nrows * kFBB * 1024 * sizeof(_Float16);
  const size_t bpP_off     = (partP_off + partP_bytes + 511) & ~(size_t)511;
  const size_t ws_P = bpP_off + bpA_bytes;                 // ~13.8 MB

  // path A layout: xp | acc(f32) | bp
  const size_t accA_off  = (xpA_bytes + 511) & ~(size_t)511;
  const size_t accA_bytes = (size_t)kAcc * sizeof(float);
  const size_t bpA_off   = (accA_off + accA_bytes + 511) & ~(size_t)511;
  const size_t ws_A = bpA_off + bpA_bytes;                 // ~10.8 MB

  // path B layout
  const int xpsB = (kTPadB - 1) * kHop + kcap + 256;
  const size_t xpB_bytes = (size_t)kB * xpsB * sizeof(_Float16);
  const size_t accB_off  = (xpB_bytes + 511) & ~(size_t)511;
  const size_t accB_bytes = (size_t)kAccB * sizeof(float);
  const size_t ws_B = accB_off + accB_bytes;

  const int nbx = (kB * (xpsA / 8) + 255) / 256;   // audio blocks (8 el/thr)
  const int nbp = (tot + 3) / 4;                   // bpack blocks (4 chunks ea)

  if (ws_size >= ws_P) {
    // ---- path P: partial-store split-K, no atomics ----
    _Float16* xp   = (_Float16*)d_ws;
    _Float16* part = (_Float16*)((char*)d_ws + partP_off);
    _Float16* bp   = (_Float16*)((char*)d_ws + bpP_off);

    prep_fused<<<nbx + nbp, 256, 0, stream>>>(
        x, kr, ki, xp, bp, (float*)part /*unused*/, pad, xpsA, nmax,
        nbx, nbp, jc);
    {
      cqt_mfma_t<true><<<(NW + 3) / 4, 256, 0, stream>>>(
          bp, xp, nullptr, part, xpsA, NW, jc);
    }
    {
      dim3 grid(kFBB, 3);    // 11 g16 waves per (fb,b) in 3 4-wave WGs
      cqt_mag_part<<<grid, 256, 0, stream>>>(part, out, jc);
    }
    return;
  }

  if (ws_size >= ws_A) {
    // ---- path A: atomic split-K ----
    _Float16* xp = (_Float16*)d_ws;
    float* accb  = (float*)((char*)d_ws + accA_off);
    _Float16* bp = (_Float16*)((char*)d_ws + bpA_off);

    const int nba = (kAcc / 4 + 255) / 256;
    prep_fused<<<nbx + nbp + nba, 256, 0, stream>>>(
        x, kr, ki, xp, bp, accb, pad, xpsA, nmax, nbx, nbp, jc);
    {
      cqt_mfma_t<false><<<(NW + 3) / 4, 256, 0, stream>>>(
          bp, xp, accb, nullptr, xpsA, NW, jc);
    }
    {
      const int total = kB * kT * kBins;
      cqt_mag4<<<(total / 4 + 255) / 256, 256, 0, stream>>>(accb, out);
    }
    return;
  }

  if (ws_size >= ws_B) {
    // ---- path B (round-3, verified ~224us) ----
    _Float16* xp = (_Float16*)d_ws;
    float* accb  = (float*)((char*)d_ws + accB_off);
    Jobs jt;
    int nj = 0;
    for (int g = 0; g < 11; ++g) {
      const int gk0 = 16 * g;
      const double f0 = 32.7 * exp2((double)gk0 / 24.0);
      const int N = (int)ceil(Q * (double)kSR / f0) + 8;
      int lo = nmax - N;
      if (lo < 0) lo = 0;
      lo = (lo / 2048) * 2048;
      for (int s = lo; s < kcap && nj < 48; s += 2048) {
        jt.k0[nj] = gk0;
        jt.lo[nj] = s;
        jt.hi[nj] = (s + 2048 < kcap) ? s + 2048 : kcap;
        ++nj;
      }
    }
    jt.n = nj;
    hipMemsetAsync(accb, 0, accB_bytes, stream);
    {
      const int total = kB * (xpsB / 2);
      prep_x_kernel<<<(total + 255) / 256, 256, 0, stream>>>(x, xp, pad, xpsB);
    }
    {
      dim3 grid(nj, kTPadB / 256, kB);
      cqt_mfma_kernel<<<grid, 256, 0, stream>>>(kr, ki, xp, accb, nmax, xpsB, jt);
    }
    {
      const int total = kB * kT * kBins;
      cqt_mag_final<<<(total + 255) / 256, 256, 0, stream>>>(
          accb, out, kTPadB, kBinPadB);
    }
    return;
  }

  // ---- path C: fp32 fallback ----
  {
    const int blocks = fb32::kWaves / 4;
    cqt_mag_kernel<<<blocks, 256, 0, stream>>>(x, kr, ki, out, nmax, pad);
  }
}

// Round 6
// 123.407 us; speedup vs baseline: 1.1989x; 1.1768x over previous
//
#include <hip/hip_runtime.h>
#include <math.h>

// HarmonicCQT via f16 MFMA: out[b,t,k] = |sum_n xpad[t*512+n] * (kr[k,n]+i*ki[k,n])|
//
// R19: R14 LDS structure + {B in registers w/ cross-barrier ping-pong,
// launch_bounds(256,4), 48-chunk slices (ns=19)}.
// Evidence: R14 (A+B LDS-DMA, 2-barrier, 64-frame WG) = best measured total
// (119.8us, main ~45us). R15-R18 redesigns all regressed; R18's VGPR=64
// showed the compiler collapsing manual reg pipelines without a bounds cap.
// Here: A keeps the verified DMA double-buffer (4-wave reuse); B (zero
// cross-wave reuse) is loaded global->reg for chunk c+2 BEFORE chunk c's
// MFMAs (sched_barrier-pinned), giving it a full iteration+barrier to land.
// Per-iter DMA 6->2/wave, LDS 48->16KB, grid 484->836 WGs (~3.3/CU).
//
// Path P, 3 dispatches, NO atomics:
//   1. prep_fused   : audio->f16 xp + B-fragment pack
//   2. cqt_mfma_t<true> : pipelined MFMA, 64 frames/WG; epilogue = 4x16B f16
//        partial stores to an exclusive per-(slice,fb,b,wave) region.
//   3. cqt_mag_part : sum 15/3/1 slice partials -> magnitude -> out
// Path A: atomic split-K (same main kernel, atomic epilogue).
// Path B: round-3 LDS-staging MFMA kernel (verified, ~224us).
// Path C: verified fp32 kernel (~370us).
//
// MFMA 16x16x32 layouts (verified rounds 3-13, absmax 4.9e-4):
//   A[m=lane&15][k=(lane>>4)*8+j], B[k=(lane>>4)*8+j][n=lane&15],
//   C/D: col=lane&15, row=(lane>>4)*4+reg.
// bp layout per 16-bin chunk (32 K-cols): 2048B = [64 lanes x 16B re][64 x 16B im]
// Partial layout: slot = ((sx*44 + fbb)*4 + wave); 2048 halfs per slot,
// lane l at slot*2048 + l*32, within-lane order [tl][r][re/im], tl=0..3.

namespace {
constexpr int kSR    = 22050;
constexpr int kHop   = 512;
constexpr int kBins  = 168;
constexpr int kT     = 689;
constexpr int kB     = 4;
constexpr int kS     = 352768;
constexpr float kKScale    = 4096.0f;
constexpr float kKScaleInv = 1.0f / 4096.0f;
constexpr int kG16 = 11;              // 16-bin groups (g10 = bins 160..167)
constexpr int kFBB = 44;              // fb(11, 64 frames each) * b(4)
constexpr int kAcc = kB * kT * kBins * 2;   // path-A split-K accumulator
// path B layout
constexpr int kTPadB   = 768;
constexpr int kBinPadB = 176;
constexpr int kAccB    = kB * kTPadB * kBinPadB * 2;
}

typedef _Float16 half8 __attribute__((ext_vector_type(8)));
typedef _Float16 half2v __attribute__((ext_vector_type(2)));
typedef float floatx4 __attribute__((ext_vector_type(4)));

struct Jobs {          // path B job table
  int k0[48];
  int lo[48];
  int hi[48];
  int n;
};

struct JobsC {         // path P/A tables
  int lo16[kG16];      // support start col per 16-bin group (256-aligned)
  int cb16[kG16];      // chunk-prefix per group (bp indexing)
  int mlo[3];          // macro-group (64-bin) support start col
  int sm[24];          // per slice: macro id
  int slo[24];         // per slice: chunk range [slo,shi) rel. to mlo (even)
  int shi[24];
  int sbeg[3];         // first slice index of macro
  int scnt[3];         // slice count of macro
  int ns;
  int totch;
};

__device__ inline void atomAddF(float* p, float v) {
  __hip_atomic_fetch_add(p, v, __ATOMIC_RELAXED, __HIP_MEMORY_SCOPE_AGENT);
}

typedef __attribute__((address_space(3))) unsigned int lds_uint;
typedef __attribute__((address_space(1))) const unsigned int glb_uint;
__device__ __forceinline__ void dma16(const void* g, void* l) {
  __builtin_amdgcn_global_load_lds((glb_uint*)g, (lds_uint*)l, 16, 0, 0);
}

// ---- fused prep: [0,nbx) audio | [nbx,nbx+nbp) bpack | [.., +nba) zero acc ----
__global__ __launch_bounds__(256) void prep_fused(
    const float* __restrict__ x, const float* __restrict__ kr,
    const float* __restrict__ ki, _Float16* __restrict__ xp,
    _Float16* __restrict__ bp, float* __restrict__ accb,
    const int pad, const int xps, const int nmax,
    const int nbx, const int nbp, const JobsC jt) {
  int bid = blockIdx.x;
  const int tid = threadIdx.x;

  if (bid < nbx) {
    // --- padded f16 audio: 8 elements/thread, one 16B store ---
    const int octx = xps >> 3;
    const int gid = bid * 256 + tid;
    if (gid >= kB * octx) return;
    const int b = gid / octx;
    const int i = (gid - b * octx) * 8;
    const float* xb = x + (size_t)b * kS - pad;
    half8 h;
    #pragma unroll
    for (int j = 0; j < 8; ++j) {
      const int e = i + j;
      h[j] = (e >= pad && e < pad + kS) ? (_Float16)xb[e] : (_Float16)0.f;
    }
    *(half8*)&xp[(size_t)b * xps + i] = h;
    return;
  }
  bid -= nbx;

  if (bid < nbp) {
    // --- B-fragment pack: 64 threads -> one 16-bin chunk (re+im) ---
    const int chunkid = bid * 4 + (tid >> 6);
    const int lane = tid & 63;
    if (chunkid >= jt.totch) return;
    int g = 0;
    #pragma unroll
    for (int j = 1; j < kG16; ++j)
      if (chunkid >= jt.cb16[j]) g = j;
    const int c = chunkid - jt.cb16[g];
    const int mm = lane & 15;
    const int q  = lane >> 4;
    const int bin  = g * 16 + mm;
    const int col0 = jt.lo16[g] + c * 32 + q * 8;
    const bool binok = (bin < kBins);
    const float* rowr = kr + (size_t)bin * nmax;
    const float* rowi = ki + (size_t)bin * nmax;
    half8 hre, him;
    #pragma unroll
    for (int j = 0; j < 8; ++j) {
      const int col = col0 + j;
      const bool ok = binok && (col < nmax);
      hre[j] = ok ? (_Float16)(rowr[col] * kKScale) : (_Float16)0.f;
      him[j] = ok ? (_Float16)(rowi[col] * kKScale) : (_Float16)0.f;
    }
    _Float16* dst = bp + (size_t)chunkid * 1024 + lane * 8;
    *(half8*)dst = hre;
    *(half8*)(dst + 512) = him;
    return;
  }
  bid -= nbp;

  // --- zero split-K accumulator (path A only; nba=0 in path P) ---
  const int idx = (bid * 256 + tid) * 4;
  if (idx < kAcc)
    *(floatx4*)&accb[idx] = (floatx4){0.f, 0.f, 0.f, 0.f};
}

// ---- main: A-in-LDS dbuf DMA + B reg ping-pong across barrier (R19) ----
// PARTIAL=true : epilogue = exclusive f16 partial stores (no atomics)
// PARTIAL=false: epilogue = guarded agent-atomic split-K
// LDS per buffer (halfs): A regions r=cc*4+tl (16 rows x 32 cols each), r=0..7,
//   at [0,4096). B is per-lane fragment-packed in global; chunk c+2's 4 half8
//   are loaded to regs BEFORE chunk c's MFMAs (one iter + barrier to land).
#define BLD(S, c)                                                      \
  { const _Float16* bs_ = bgrp + (size_t)(c) * 1024;                   \
    S##0 = *(const half8*)(bs_);                                       \
    S##1 = *(const half8*)(bs_ + 512);                                 \
    S##2 = *(const half8*)(bs_ + 1024);                                \
    S##3 = *(const half8*)(bs_ + 1536); }

#define MMC(S, bufid)                                                  \
  { const _Float16* L_ = lds[bufid];                                   \
    _Pragma("unroll")                                                  \
    for (int cc = 0; cc < 2; ++cc) {                                   \
      const half8 Bre_ = (cc == 0) ? S##0 : S##2;                      \
      const half8 Bim_ = (cc == 0) ? S##1 : S##3;                      \
      _Pragma("unroll")                                                \
      for (int tl = 0; tl < 4; ++tl) {                                 \
        const half8 A_ = *(const half8*)(L_ + (cc * 4 + tl) * 512 + lane * 8); \
        accr[tl] = __builtin_amdgcn_mfma_f32_16x16x32_f16(A_, Bre_, accr[tl], 0, 0, 0); \
        acci[tl] = __builtin_amdgcn_mfma_f32_16x16x32_f16(A_, Bim_, acci[tl], 0, 0, 0); \
      } } }

template <bool PARTIAL>
__global__ __launch_bounds__(256, 4) void cqt_mfma_t(
    const _Float16* __restrict__ bp, const _Float16* __restrict__ xp,
    float* __restrict__ accb, _Float16* __restrict__ part,
    const int xps, const JobsC jt) {
  __shared__ _Float16 lds[2][4096];    // 2 x 8 KB, A only

  const int sx = blockIdx.y;
  const int fb = blockIdx.x >> 2;      // 0..10 (64 frames each)
  const int b  = blockIdx.x & 3;
  const int tid  = threadIdx.x;
  const int wave = tid >> 6;
  const int lane = tid & 63;
  const int mm = lane & 15;
  const int q  = lane >> 4;
  const int mac = jt.sm[sx];
  const int g16 = mac * 4 + wave;
  const bool gvalid = (g16 < kG16);
  const int mlo = jt.mlo[mac];
  const int gs = gvalid ? ((jt.lo16[g16] - mlo) >> 5) : 0;
  const int slo = jt.slo[sx];
  const int shi = jt.shi[sx];
  const int fbase = fb * 64;
  int cw0 = slo; if (gvalid && gs > cw0) cw0 = gs;   // wave's first chunk (even)

  // A-DMA source geometry: wave w stages regions r = 2w, 2w+1 (r = cc*4+tl);
  // region r = 16 rows (fbase+(r&3)*16+mm) x 32 cols ((r>>2)*32+q*8), 1KB each.
  const _Float16* xb = xp + (size_t)b * xps;
  int aoff0, aoff1;
  {
    const int r0 = wave * 2;
    int row0 = fbase + (r0 & 3) * 16 + mm;
    if (row0 > kT - 1) row0 = kT - 1;
    aoff0 = row0 * kHop + (r0 >> 2) * 32 + q * 8;
    const int r1 = r0 + 1;
    int row1 = fbase + (r1 & 3) * 16 + mm;
    if (row1 > kT - 1) row1 = kT - 1;
    aoff1 = row1 * kHop + (r1 >> 2) * 32 + q * 8;
  }
  // B frags pre-packed per-lane: chunk c re at bgrp+c*1024, im at +512
  const _Float16* bgrp =
      gvalid ? (bp + (size_t)(jt.cb16[g16] - gs) * 1024 + lane * 8)
             : (bp + lane * 8);

  floatx4 accr[4], acci[4];
  #pragma unroll
  for (int tl = 0; tl < 4; ++tl) {
    accr[tl] = (floatx4){0.f, 0.f, 0.f, 0.f};
    acci[tl] = (floatx4){0.f, 0.f, 0.f, 0.f};
  }

  auto stageA = [&](int c, int buf) {
    _Float16* L = lds[buf];
    const _Float16* xc = xb + mlo + c * 32;
    dma16(xc + aoff0, L + (wave * 2) * 512);
    dma16(xc + aoff1, L + (wave * 2 + 1) * 512);
  };

  half8 U0{}, U1{}, U2{}, U3{}, V0{}, V1{}, V2{}, V3{};

  // chunk ch is computed at parity p(ch)=((ch-slo)/2)&1: p=0 -> U, p=1 -> V.
  // Prefetch of ch happens one iteration earlier into the matching buffer.
  // All slice lengths give an even number of 2-chunk steps (24/20/12).
  stageA(slo, 0);
  if (gvalid && cw0 == slo) BLD(U, slo);
  int buf = 0;
  int c = slo;
  #pragma unroll 1
  for (; c + 2 < shi; c += 4) {
    // phase 0: chunk c in U; prefetch c+2 -> V
    __syncthreads();                     // drains A-DMA (and last B loads)
    stageA(c + 2, buf ^ 1);
    if (gvalid && c + 2 >= cw0) BLD(V, c + 2);
    __builtin_amdgcn_sched_barrier(0);   // pin B prefetch before MFMAs
    if (gvalid && c >= cw0) MMC(U, buf);
    buf ^= 1;
    // phase 1: chunk c+2 in V; prefetch c+4 -> U
    __syncthreads();
    if (c + 4 < shi) stageA(c + 4, buf ^ 1);
    if (gvalid && c + 4 < shi && c + 4 >= cw0) BLD(U, c + 4);
    __builtin_amdgcn_sched_barrier(0);
    if (gvalid && c + 2 >= cw0) MMC(V, buf);
    buf ^= 1;
  }

  if (PARTIAL) {
    // exclusive-region f16 partial stores: 4 x 16B per lane, no RMW
    _Float16* pw = part +
        (((size_t)sx * kFBB + blockIdx.x) * 4 + wave) * 2048 + lane * 32;
    #pragma unroll
    for (int tl = 0; tl < 4; ++tl) {
      half8 p;
      #pragma unroll
      for (int r = 0; r < 4; ++r) {
        p[r * 2]     = (_Float16)accr[tl][r];
        p[r * 2 + 1] = (_Float16)acci[tl][r];
      }
      *(half8*)(pw + tl * 8) = p;
    }
  } else {
    // guarded agent-atomic split-K combine
    const int bin = g16 * 16 + mm;
    if (gvalid && bin < kBins) {
      #pragma unroll
      for (int tl = 0; tl < 4; ++tl) {
        const int tb = fbase + tl * 16 + q * 4;
        #pragma unroll
        for (int r = 0; r < 4; ++r) {
          const int t = tb + r;
          if (t < kT) {
            const size_t o = (((size_t)b * kT + t) * kBins + bin) * 2;
            atomAddF(&accb[o],     accr[tl][r] * kKScaleInv);
            atomAddF(&accb[o + 1], acci[tl][r] * kKScaleInv);
          }
        }
      }
    }
  }
}
#undef BLD
#undef MMC

// ---- path P final: sum slice partials -> magnitude -> out ----
__global__ __launch_bounds__(256) void cqt_mag_part(
    const _Float16* __restrict__ part, float* __restrict__ out,
    const JobsC jt) {
  const int fbb = blockIdx.x;          // 0..43
  const int fb = fbb >> 2;
  const int b  = fbb & 3;
  const int wave = threadIdx.x >> 6;
  const int lane = threadIdx.x & 63;
  const int g16 = blockIdx.y * 4 + wave;
  if (g16 >= kG16) return;
  const int mac = g16 >> 2;
  const int w   = g16 & 3;
  const int mm = lane & 15;
  const int q  = lane >> 4;

  float a[32];
  #pragma unroll
  for (int i = 0; i < 32; ++i) a[i] = 0.f;
  const int s0 = jt.sbeg[mac];
  const int s1 = s0 + jt.scnt[mac];
  #pragma unroll 1
  for (int s = s0; s < s1; ++s) {
    const _Float16* p = part +
        (((size_t)s * kFBB + fbb) * 4 + w) * 2048 + lane * 32;
    #pragma unroll
    for (int tl = 0; tl < 4; ++tl) {
      const half8 v = *(const half8*)(p + tl * 8);
      #pragma unroll
      for (int j = 0; j < 8; ++j) a[tl * 8 + j] += (float)v[j];
    }
  }
  const int k = g16 * 16 + mm;
  if (k >= kBins) return;
  #pragma unroll
  for (int tl = 0; tl < 4; ++tl) {
    #pragma unroll
    for (int r = 0; r < 4; ++r) {
      const int t = fb * 64 + tl * 16 + q * 4 + r;
      if (t < kT) {
        const float re = a[tl * 8 + r * 2];
        const float im = a[tl * 8 + r * 2 + 1];
        out[((size_t)b * kT + t) * kBins + k] =
            sqrtf(re * re + im * im) * kKScaleInv;
      }
    }
  }
}

// ---- path A final: magnitude, 4 outputs/thread ----
__global__ __launch_bounds__(256) void cqt_mag4(
    const float* __restrict__ accb, float* __restrict__ out) {
  const int gid = (blockIdx.x * 256 + threadIdx.x) * 4;
  if (gid >= kB * kT * kBins) return;
  const floatx4 v0 = *(const floatx4*)&accb[gid * 2];
  const floatx4 v1 = *(const floatx4*)&accb[gid * 2 + 4];
  floatx4 o;
  o[0] = sqrtf(v0[0] * v0[0] + v0[1] * v0[1]);
  o[1] = sqrtf(v0[2] * v0[2] + v0[3] * v0[3]);
  o[2] = sqrtf(v1[0] * v1[0] + v1[1] * v1[1]);
  o[3] = sqrtf(v1[2] * v1[2] + v1[3] * v1[3]);
  *(floatx4*)&out[gid] = o;
}

// ---- path B final: magnitude (layout-parametric) ----
__global__ __launch_bounds__(256) void cqt_mag_final(
    const float* __restrict__ accb, float* __restrict__ out,
    const int tp, const int kp) {
  int gid = blockIdx.x * 256 + threadIdx.x;
  if (gid >= kB * kT * kBins) return;
  const int k = gid % kBins;
  const int r = gid / kBins;
  const int t = r % kT;
  const int b = r / kT;
  const float2 v = ((const float2*)accb)[((size_t)b * tp + t) * kp + k];
  out[gid] = sqrtf(v.x * v.x + v.y * v.y);
}

// ================= path B: round-3 LDS-staging MFMA (verified) =============
__global__ __launch_bounds__(256) void prep_x_kernel(
    const float* __restrict__ x, _Float16* __restrict__ xp,
    const int pad, const int xps) {
  const int halfx = xps >> 1;
  int gid = blockIdx.x * 256 + threadIdx.x;
  if (gid >= kB * halfx) return;
  const int b = gid / halfx;
  const int i = (gid - b * halfx) * 2;
  float v0 = 0.f, v1 = 0.f;
  if (i     >= pad && i     < pad + kS) v0 = x[(size_t)b * kS + (i - pad)];
  if (i + 1 >= pad && i + 1 < pad + kS) v1 = x[(size_t)b * kS + (i + 1 - pad)];
  half2v h; h.x = (_Float16)v0; h.y = (_Float16)v1;
  *(half2v*)&xp[(size_t)b * xps + i] = h;
}

__global__ __launch_bounds__(256) void cqt_mfma_kernel(
    const float* __restrict__ kr, const float* __restrict__ ki,
    const _Float16* __restrict__ xp, float* __restrict__ accb,
    const int nmax, const int xps, const Jobs jt) {
  __shared__ _Float16 Bs[2][16][264];
  const int jb = blockIdx.x;
  const int k0   = jt.k0[jb];
  const int n_lo = jt.lo[jb];
  const int n_hi = jt.hi[jb];
  const int b  = blockIdx.z;
  const int fb = blockIdx.y;
  const int tid  = threadIdx.x;
  const int lane = tid & 63;
  const int wave = tid >> 6;
  const int m = lane & 15;
  const int q = lane >> 4;
  const int sbin = tid >> 4;
  const int scol = tid & 15;
  const int gbin = k0 + sbin;
  const bool binok = (gbin < kBins);
  const float* rowr = kr + (size_t)gbin * nmax;
  const float* rowi = ki + (size_t)gbin * nmax;
  const int fbase = fb * 256 + wave * 64;
  const _Float16* ax =
      xp + (size_t)b * xps + (size_t)(fbase + m) * kHop + q * 8;
  floatx4 accr[4], acci[4];
  #pragma unroll
  for (int tl = 0; tl < 4; ++tl) {
    accr[tl] = (floatx4){0.f, 0.f, 0.f, 0.f};
    acci[tl] = (floatx4){0.f, 0.f, 0.f, 0.f};
  }
  for (int n0r = n_lo; n0r < n_hi; n0r += 256) {
    __syncthreads();
    #pragma unroll
    for (int c = 0; c < 16; ++c) {
      const int col = n0r + scol + c * 16;
      const bool ok = binok && (col < nmax);
      const float vr = ok ? rowr[col] : 0.f;
      const float vi = ok ? rowi[col] : 0.f;
      Bs[0][sbin][scol + c * 16] = (_Float16)(vr * kKScale);
      Bs[1][sbin][scol + c * 16] = (_Float16)(vi * kKScale);
    }
    __syncthreads();
    const _Float16* axr = ax + n0r;
    #pragma unroll
    for (int c = 0; c < 8; ++c) {
      const int ko = c * 32 + q * 8;
      const half8 br = *(const half8*)&Bs[0][m][ko];
      const half8 bi = *(const half8*)&Bs[1][m][ko];
      #pragma unroll
      for (int tl = 0; tl < 4; ++tl) {
        const half8 a = *(const half8*)(axr + tl * 16 * kHop + c * 32);
        accr[tl] = __builtin_amdgcn_mfma_f32_16x16x32_f16(a, br, accr[tl], 0, 0, 0);
        acci[tl] = __builtin_amdgcn_mfma_f32_16x16x32_f16(a, bi, acci[tl], 0, 0, 0);
      }
    }
  }
  #pragma unroll
  for (int tl = 0; tl < 4; ++tl) {
    #pragma unroll
    for (int rr = 0; rr < 4; ++rr) {
      const int t = fbase + tl * 16 + q * 4 + rr;
      const size_t o = (((size_t)b * kTPadB + t) * kBinPadB + (k0 + m)) * 2;
      atomAddF(&accb[o],     accr[tl][rr] * kKScaleInv);
      atomAddF(&accb[o + 1], acci[tl][rr] * kKScaleInv);
    }
  }
}

// ================= path C: verified fp32 kernel (round 2) ==================
namespace fb32 {
constexpr int TT = 8;
constexpr int KG = 4;
constexpr int kTTiles  = (kT + TT - 1) / TT;
constexpr int kKGroups = kBins / KG;
constexpr int kWaves   = kB * kTTiles * kKGroups;
}

__global__ __launch_bounds__(256) void cqt_mag_kernel(
    const float* __restrict__ x,
    const float* __restrict__ kr,
    const float* __restrict__ ki,
    float* __restrict__ out,
    const int nmax, const int pad) {
  using namespace fb32;
  const int wave = (blockIdx.x << 2) + (threadIdx.x >> 6);
  const int lane = threadIdx.x & 63;
  if (wave >= kWaves) return;
  const int kg    = wave / (kB * kTTiles);
  const int rem   = wave - kg * (kB * kTTiles);
  const int b     = rem / kTTiles;
  const int ttile = rem - b * kTTiles;
  const int k0 = kg * KG;
  const int t0 = ttile * TT;
  const double Q  = 1.0 / (exp2(1.0 / 24.0) - 1.0);
  const double f0 = 32.7 * exp2((double)k0 / 24.0);
  int N = (int)ceil(Q * (double)kSR / f0) + 8;
  int full_start = nmax - N;
  if (full_start < 0) full_start = 0;
  int tbase[TT], lo[TT], t_last;
  { int t = t0 + TT - 1; if (t > kT - 1) t = kT - 1; t_last = t; }
  #pragma unroll
  for (int tt = 0; tt < TT; ++tt) {
    int t = t0 + tt; if (t > kT - 1) t = kT - 1;
    tbase[tt] = b * kS + t * kHop - pad;
    lo[tt]    = pad - t * kHop;
  }
  int head_start = pad - t_last * kHop;
  if (head_start < full_start) head_start = full_start;
  int safe = pad - t0 * kHop;
  if (safe < head_start) safe = head_start;
  int body_start = nmax - ((nmax - safe) & ~63);
  float accr[TT][KG], acci[TT][KG];
  #pragma unroll
  for (int tt = 0; tt < TT; ++tt)
    #pragma unroll
    for (int kk = 0; kk < KG; ++kk) { accr[tt][kk] = 0.f; acci[tt][kk] = 0.f; }
  for (int n = body_start - 64; n > head_start - 64; n -= 64) {
    const int nn = n + lane;
    const bool kok = (nn >= 0);
    float krv[KG], kiv[KG];
    #pragma unroll
    for (int kk = 0; kk < KG; ++kk) {
      krv[kk] = kok ? kr[(k0 + kk) * nmax + nn] : 0.f;
      kiv[kk] = kok ? ki[(k0 + kk) * nmax + nn] : 0.f;
    }
    float a[TT];
    #pragma unroll
    for (int tt = 0; tt < TT; ++tt)
      a[tt] = (nn >= lo[tt]) ? x[tbase[tt] + nn] : 0.f;
    #pragma unroll
    for (int tt = 0; tt < TT; ++tt)
      #pragma unroll
      for (int kk = 0; kk < KG; ++kk) {
        accr[tt][kk] = fmaf(a[tt], krv[kk], accr[tt][kk]);
        acci[tt][kk] = fmaf(a[tt], kiv[kk], acci[tt][kk]);
      }
  }
  for (int n = body_start; n < nmax; n += 64) {
    const int nn = n + lane;
    float krv[KG], kiv[KG];
    #pragma unroll
    for (int kk = 0; kk < KG; ++kk) {
      krv[kk] = kr[(k0 + kk) * nmax + nn];
      kiv[kk] = ki[(k0 + kk) * nmax + nn];
    }
    float a[TT];
    #pragma unroll
    for (int tt = 0; tt < TT; ++tt)
      a[tt] = x[tbase[tt] + nn];
    #pragma unroll
    for (int tt = 0; tt < TT; ++tt)
      #pragma unroll
      for (int kk = 0; kk < KG; ++kk) {
        accr[tt][kk] = fmaf(a[tt], krv[kk], accr[tt][kk]);
        acci[tt][kk] = fmaf(a[tt], kiv[kk], acci[tt][kk]);
      }
  }
  #pragma unroll
  for (int tt = 0; tt < TT; ++tt) {
    #pragma unroll
    for (int kk = 0; kk < KG; ++kk) {
      float r = accr[tt][kk];
      float i = acci[tt][kk];
      #pragma unroll
      for (int s = 32; s > 0; s >>= 1) {
        r += __shfl_xor(r, s, 64);
        i += __shfl_xor(i, s, 64);
      }
      if (lane == 0) {
        const int t = t0 + tt;
        if (t < kT)
          out[(b * kT + t) * kBins + (k0 + kk)] = sqrtf(r * r + i * i);
      }
    }
  }
}
// ============================================================================

extern "C" void kernel_launch(void* const* d_in, const int* in_sizes, int n_in,
                              void* d_out, int out_size, void* d_ws, size_t ws_size,
                              hipStream_t stream) {
  const float* x  = (const float*)d_in[0];   // [4, 1, 352768]
  const float* kr = (const float*)d_in[1];   // [168, nmax]
  const float* ki = (const float*)d_in[2];   // [168, nmax]
  float* out = (float*)d_out;                // [4, 1, 689, 168]

  const int nmax = in_sizes[1] / kBins;      // 23013 (runtime truth)
  const int pad  = nmax - kHop;

  const int kcap = ((nmax + 255) / 256) * 256;   // 23040
  const double Q = 1.0 / (exp2(1.0 / 24.0) - 1.0);

  // ---- path P/A tables ----
  JobsC jc;
  int tot = 0;
  for (int g = 0; g < kG16; ++g) {
    const double f0 = 32.7 * exp2((double)(16 * g) / 24.0);
    const int N = (int)ceil(Q * (double)kSR / f0) + 8;
    int lo = nmax - N;
    if (lo < 0) lo = 0;
    lo &= ~255;
    jc.lo16[g] = lo;
    jc.cb16[g] = tot;
    tot += (kcap - lo) / 32;
  }
  jc.totch = tot;                        // ~1984 chunks
  // ns=19 slice table (48-chunk slices -> 15/3/1; lengths 48/40/24 give an
  // even number of 2-chunk steps, required by the main loop's 2x unroll)
  int ns = 0;
  for (int m = 0; m < 3; ++m) {
    jc.mlo[m] = jc.lo16[4 * m];
    jc.sbeg[m] = ns;
    const int C = (kcap - jc.mlo[m]) / 32;       // 720 / 120 / 24
    const int nsl = (C + 47) / 48;               // 15 / 3 / 1
    const int len = ((C + nsl - 1) / nsl + 1) & ~1;
    for (int s = 0; s < nsl && ns < 24; ++s) {
      const int lo = s * len;
      if (lo >= C) break;
      int hi = lo + len;
      if (hi > C) hi = C;
      jc.sm[ns] = m; jc.slo[ns] = lo; jc.shi[ns] = hi;
      ++ns;
    }
    jc.scnt[m] = ns - jc.sbeg[m];
  }
  jc.ns = ns;                            // 19 expected

  // ---- shared ws pieces ----
  const int xpsA = (kT - 1) * kHop + kcap + 256;           // 375,552 (%8==0)
  const size_t xpA_bytes = (size_t)kB * xpsA * sizeof(_Float16);
  const size_t bpA_bytes = (size_t)tot * 2048;

  // path P layout: xp | part(f16) | bp
  const size_t partP_off   = (xpA_bytes + 511) & ~(size_t)511;
  const size_t partP_bytes = (size_t)ns * kFBB * 4 * 2048 * sizeof(_Float16);
  const size_t bpP_off     = (partP_off + partP_bytes + 511) & ~(size_t)511;
  const size_t ws_P = bpP_off + bpA_bytes;                 // ~20.8 MB

  // path A layout: xp | acc(f32) | bp
  const size_t accA_off  = (xpA_bytes + 511) & ~(size_t)511;
  const size_t accA_bytes = (size_t)kAcc * sizeof(float);
  const size_t bpA_off   = (accA_off + accA_bytes + 511) & ~(size_t)511;
  const size_t ws_A = bpA_off + bpA_bytes;                 // ~10.8 MB

  // path B layout
  const int xpsB = (kTPadB - 1) * kHop + kcap + 256;
  const size_t xpB_bytes = (size_t)kB * xpsB * sizeof(_Float16);
  const size_t accB_off  = (xpB_bytes + 511) & ~(size_t)511;
  const size_t accB_bytes = (size_t)kAccB * sizeof(float);
  const size_t ws_B = accB_off + accB_bytes;

  const int nbx = (kB * (xpsA / 8) + 255) / 256;   // audio blocks (8 el/thr)
  const int nbp = (tot + 3) / 4;                   // bpack blocks (4 chunks ea)

  if (ws_size >= ws_P) {
    // ---- path P: partial-store split-K, no atomics ----
    _Float16* xp   = (_Float16*)d_ws;
    _Float16* part = (_Float16*)((char*)d_ws + partP_off);
    _Float16* bp   = (_Float16*)((char*)d_ws + bpP_off);

    prep_fused<<<nbx + nbp, 256, 0, stream>>>(
        x, kr, ki, xp, bp, (float*)part /*unused*/, pad, xpsA, nmax,
        nbx, nbp, jc);
    {
      dim3 grid(kFBB, ns);
      cqt_mfma_t<true><<<grid, 256, 0, stream>>>(
          bp, xp, nullptr, part, xpsA, jc);
    }
    {
      dim3 grid(kFBB, 3);    // 11 g16 waves per (fb,b) in 3 4-wave WGs
      cqt_mag_part<<<grid, 256, 0, stream>>>(part, out, jc);
    }
    return;
  }

  if (ws_size >= ws_A) {
    // ---- path A: atomic split-K ----
    _Float16* xp = (_Float16*)d_ws;
    float* accb  = (float*)((char*)d_ws + accA_off);
    _Float16* bp = (_Float16*)((char*)d_ws + bpA_off);

    const int nba = (kAcc / 4 + 255) / 256;
    prep_fused<<<nbx + nbp + nba, 256, 0, stream>>>(
        x, kr, ki, xp, bp, accb, pad, xpsA, nmax, nbx, nbp, jc);
    {
      dim3 grid(kFBB, ns);
      cqt_mfma_t<false><<<grid, 256, 0, stream>>>(
          bp, xp, accb, nullptr, xpsA, jc);
    }
    {
      const int total = kB * kT * kBins;
      cqt_mag4<<<(total / 4 + 255) / 256, 256, 0, stream>>>(accb, out);
    }
    return;
  }

  if (ws_size >= ws_B) {
    // ---- path B (round-3, verified ~224us) ----
    _Float16* xp = (_Float16*)d_ws;
    float* accb  = (float*)((char*)d_ws + accB_off);
    Jobs jt;
    int nj = 0;
    for (int g = 0; g < 11; ++g) {
      const int gk0 = 16 * g;
      const double f0 = 32.7 * exp2((double)gk0 / 24.0);
      const int N = (int)ceil(Q * (double)kSR / f0) + 8;
      int lo = nmax - N;
      if (lo < 0) lo = 0;
      lo = (lo / 2048) * 2048;
      for (int s = lo; s < kcap && nj < 48; s += 2048) {
        jt.k0[nj] = gk0;
        jt.lo[nj] = s;
        jt.hi[nj] = (s + 2048 < kcap) ? s + 2048 : kcap;
        ++nj;
      }
    }
    jt.n = nj;
    hipMemsetAsync(accb, 0, accB_bytes, stream);
    {
      const int total = kB * (xpsB / 2);
      prep_x_kernel<<<(total + 255) / 256, 256, 0, stream>>>(x, xp, pad, xpsB);
    }
    {
      dim3 grid(nj, kTPadB / 256, kB);
      cqt_mfma_kernel<<<grid, 256, 0, stream>>>(kr, ki, xp, accb, nmax, xpsB, jt);
    }
    {
      const int total = kB * kT * kBins;
      cqt_mag_final<<<(total + 255) / 256, 256, 0, stream>>>(
          accb, out, kTPadB, kBinPadB);
    }
    return;
  }

  // ---- path C: fp32 fallback ----
  {
    const int blocks = fb32::kWaves / 4;
    cqt_mag_kernel<<<blocks, 256, 0, stream>>>(x, kr, ki, out, nmax, pad);
  }
}

// Round 7
// 111.155 us; speedup vs baseline: 1.3310x; 1.1102x over previous
//
#include <hip/hip_runtime.h>
#include <math.h>

// HarmonicCQT via f16 MFMA: out[b,t,k] = |sum_n xpad[t*512+n] * (kr[k,n]+i*ki[k,n])|
//
// R20: R19 structure + COALESCED-SWIZZLED A staging.
// Every prior round paid a 64-lines-per-instruction A gather (16B/lane at 1KB
// row stride) -- ~16us of L1 issue across the dispatch. Now the A tile
// (64 rows x 64 cols per stage) is staged row-major: dma16's forced-linear
// LDS dest (u=r*256+w*64+l -> row=u>>3, c16=u&7) is fed by a PRE-SWIZZLED
// per-lane global source (c16_src = (u&7)^(row&7)); each 8-lane group fetches
// one 128B-aligned line of one frame row => 8 lines/instr (8x fewer L1
// transactions). MFMA A-read uses the matching XOR ((cc*4+q)^(mm&7)) -- 2-way
// bank aliasing = free. B stays in registers with the R19 cross-barrier
// ping-pong. LDS 16KB, launch_bounds(256,4), ns=19 slices.
//
// Path P, 3 dispatches, NO atomics:
//   1. prep_fused   : audio->f16 xp + B-fragment pack
//   2. cqt_mfma_t<true> : pipelined MFMA, 64 frames/WG; epilogue = 4x16B f16
//        partial stores to an exclusive per-(slice,fb,b,wave) region.
//   3. cqt_mag_part : sum 15/3/1 slice partials -> magnitude -> out
// Path A: atomic split-K (same main kernel, atomic epilogue).
// Path B: round-3 LDS-staging MFMA kernel (verified, ~224us).
// Path C: verified fp32 kernel (~370us).
//
// MFMA 16x16x32 layouts (verified rounds 3-13, absmax 4.9e-4):
//   A[m=lane&15][k=(lane>>4)*8+j], B[k=(lane>>4)*8+j][n=lane&15],
//   C/D: col=lane&15, row=(lane>>4)*4+reg.
// bp layout per 16-bin chunk (32 K-cols): 2048B = [64 lanes x 16B re][64 x 16B im]
// A-LDS tile per buffer: [64 rows][8 c16] halfs, byte = row*128 + (c16^(row&7))*16.
// Partial layout: slot = ((sx*44 + fbb)*4 + wave); 2048 halfs per slot,
// lane l at slot*2048 + l*32, within-lane order [tl][r][re/im], tl=0..3.

namespace {
constexpr int kSR    = 22050;
constexpr int kHop   = 512;
constexpr int kBins  = 168;
constexpr int kT     = 689;
constexpr int kB     = 4;
constexpr int kS     = 352768;
constexpr float kKScale    = 4096.0f;
constexpr float kKScaleInv = 1.0f / 4096.0f;
constexpr int kG16 = 11;              // 16-bin groups (g10 = bins 160..167)
constexpr int kFBB = 44;              // fb(11, 64 frames each) * b(4)
constexpr int kAcc = kB * kT * kBins * 2;   // path-A split-K accumulator
// path B layout
constexpr int kTPadB   = 768;
constexpr int kBinPadB = 176;
constexpr int kAccB    = kB * kTPadB * kBinPadB * 2;
}

typedef _Float16 half8 __attribute__((ext_vector_type(8)));
typedef _Float16 half2v __attribute__((ext_vector_type(2)));
typedef float floatx4 __attribute__((ext_vector_type(4)));

struct Jobs {          // path B job table
  int k0[48];
  int lo[48];
  int hi[48];
  int n;
};

struct JobsC {         // path P/A tables
  int lo16[kG16];      // support start col per 16-bin group (256-aligned)
  int cb16[kG16];      // chunk-prefix per group (bp indexing)
  int mlo[3];          // macro-group (64-bin) support start col
  int sm[24];          // per slice: macro id
  int slo[24];         // per slice: chunk range [slo,shi) rel. to mlo (even)
  int shi[24];
  int sbeg[3];         // first slice index of macro
  int scnt[3];         // slice count of macro
  int ns;
  int totch;
};

__device__ inline void atomAddF(float* p, float v) {
  __hip_atomic_fetch_add(p, v, __ATOMIC_RELAXED, __HIP_MEMORY_SCOPE_AGENT);
}

typedef __attribute__((address_space(3))) unsigned int lds_uint;
typedef __attribute__((address_space(1))) const unsigned int glb_uint;
__device__ __forceinline__ void dma16(const void* g, void* l) {
  __builtin_amdgcn_global_load_lds((glb_uint*)g, (lds_uint*)l, 16, 0, 0);
}

// ---- fused prep: [0,nbx) audio | [nbx,nbx+nbp) bpack | [.., +nba) zero acc ----
__global__ __launch_bounds__(256) void prep_fused(
    const float* __restrict__ x, const float* __restrict__ kr,
    const float* __restrict__ ki, _Float16* __restrict__ xp,
    _Float16* __restrict__ bp, float* __restrict__ accb,
    const int pad, const int xps, const int nmax,
    const int nbx, const int nbp, const JobsC jt) {
  int bid = blockIdx.x;
  const int tid = threadIdx.x;

  if (bid < nbx) {
    // --- padded f16 audio: 8 elements/thread, one 16B store ---
    const int octx = xps >> 3;
    const int gid = bid * 256 + tid;
    if (gid >= kB * octx) return;
    const int b = gid / octx;
    const int i = (gid - b * octx) * 8;
    const float* xb = x + (size_t)b * kS - pad;
    half8 h;
    #pragma unroll
    for (int j = 0; j < 8; ++j) {
      const int e = i + j;
      h[j] = (e >= pad && e < pad + kS) ? (_Float16)xb[e] : (_Float16)0.f;
    }
    *(half8*)&xp[(size_t)b * xps + i] = h;
    return;
  }
  bid -= nbx;

  if (bid < nbp) {
    // --- B-fragment pack: 64 threads -> one 16-bin chunk (re+im) ---
    const int chunkid = bid * 4 + (tid >> 6);
    const int lane = tid & 63;
    if (chunkid >= jt.totch) return;
    int g = 0;
    #pragma unroll
    for (int j = 1; j < kG16; ++j)
      if (chunkid >= jt.cb16[j]) g = j;
    const int c = chunkid - jt.cb16[g];
    const int mm = lane & 15;
    const int q  = lane >> 4;
    const int bin  = g * 16 + mm;
    const int col0 = jt.lo16[g] + c * 32 + q * 8;
    const bool binok = (bin < kBins);
    const float* rowr = kr + (size_t)bin * nmax;
    const float* rowi = ki + (size_t)bin * nmax;
    half8 hre, him;
    #pragma unroll
    for (int j = 0; j < 8; ++j) {
      const int col = col0 + j;
      const bool ok = binok && (col < nmax);
      hre[j] = ok ? (_Float16)(rowr[col] * kKScale) : (_Float16)0.f;
      him[j] = ok ? (_Float16)(rowi[col] * kKScale) : (_Float16)0.f;
    }
    _Float16* dst = bp + (size_t)chunkid * 1024 + lane * 8;
    *(half8*)dst = hre;
    *(half8*)(dst + 512) = him;
    return;
  }
  bid -= nbp;

  // --- zero split-K accumulator (path A only; nba=0 in path P) ---
  const int idx = (bid * 256 + tid) * 4;
  if (idx < kAcc)
    *(floatx4*)&accb[idx] = (floatx4){0.f, 0.f, 0.f, 0.f};
}

// ---- main: coalesced-swizzled A LDS dbuf + B reg ping-pong (R20) ----
// PARTIAL=true : epilogue = exclusive f16 partial stores (no atomics)
// PARTIAL=false: epilogue = guarded agent-atomic split-K
// A tile/buffer: 64 rows x 64 cols (2 chunks). Linear unit u = r*256+w*64+l
// -> LDS (row=u>>3, c16_dest=u&7); lane fetches global c16_src = (u&7)^(row&7)
// so LDS holds the st-swizzled tile; each 8-lane group = one 128B line.
// Read: half8 at halfs row*64 + ((cc*4+q)^(mm&7))*8 (2-way bank alias = free).
#define BLD(S, c)                                                      \
  { const _Float16* bs_ = bgrp + (size_t)(c) * 1024;                   \
    S##0 = *(const half8*)(bs_);                                       \
    S##1 = *(const half8*)(bs_ + 512);                                 \
    S##2 = *(const half8*)(bs_ + 1024);                                \
    S##3 = *(const half8*)(bs_ + 1536); }

#define MMC(S, bufid)                                                  \
  { const _Float16* L_ = lds[bufid];                                   \
    _Pragma("unroll")                                                  \
    for (int cc = 0; cc < 2; ++cc) {                                   \
      const half8 Bre_ = (cc == 0) ? S##0 : S##2;                      \
      const half8 Bim_ = (cc == 0) ? S##1 : S##3;                      \
      const int cx_ = ((cc * 4 + q) ^ (mm & 7)) * 8;                   \
      _Pragma("unroll")                                                \
      for (int tl = 0; tl < 4; ++tl) {                                 \
        const half8 A_ = *(const half8*)(L_ + (tl * 16 + mm) * 64 + cx_); \
        accr[tl] = __builtin_amdgcn_mfma_f32_16x16x32_f16(A_, Bre_, accr[tl], 0, 0, 0); \
        acci[tl] = __builtin_amdgcn_mfma_f32_16x16x32_f16(A_, Bim_, acci[tl], 0, 0, 0); \
      } } }

template <bool PARTIAL>
__global__ __launch_bounds__(256, 4) void cqt_mfma_t(
    const _Float16* __restrict__ bp, const _Float16* __restrict__ xp,
    float* __restrict__ accb, _Float16* __restrict__ part,
    const int xps, const JobsC jt) {
  __shared__ _Float16 lds[2][4096];    // 2 x 8 KB, A only

  const int sx = blockIdx.y;
  const int fb = blockIdx.x >> 2;      // 0..10 (64 frames each)
  const int b  = blockIdx.x & 3;
  const int tid  = threadIdx.x;
  const int wave = tid >> 6;
  const int lane = tid & 63;
  const int mm = lane & 15;
  const int q  = lane >> 4;
  const int mac = jt.sm[sx];
  const int g16 = mac * 4 + wave;
  const bool gvalid = (g16 < kG16);
  const int mlo = jt.mlo[mac];
  const int gs = gvalid ? ((jt.lo16[g16] - mlo) >> 5) : 0;
  const int slo = jt.slo[sx];
  const int shi = jt.shi[sx];
  const int fbase = fb * 64;
  int cw0 = slo; if (gvalid && gs > cw0) cw0 = gs;   // wave's first chunk (even)

  // coalesced-swizzled A source offsets (halfs), one per dma16 round
  const _Float16* xb = xp + (size_t)b * xps;
  int asrc0, asrc1;
  {
    const int u0 = wave * 64 + lane;
    const int r0 = u0 >> 3;
    int f0 = fbase + r0; if (f0 > kT - 1) f0 = kT - 1;
    asrc0 = f0 * kHop + (((u0 & 7) ^ (r0 & 7)) * 8);
    const int u1 = 256 + wave * 64 + lane;
    const int r1 = u1 >> 3;
    int f1 = fbase + r1; if (f1 > kT - 1) f1 = kT - 1;
    asrc1 = f1 * kHop + (((u1 & 7) ^ (r1 & 7)) * 8);
  }
  // B frags pre-packed per-lane: chunk c re at bgrp+c*1024, im at +512
  const _Float16* bgrp =
      gvalid ? (bp + (size_t)(jt.cb16[g16] - gs) * 1024 + lane * 8)
             : (bp + lane * 8);

  floatx4 accr[4], acci[4];
  #pragma unroll
  for (int tl = 0; tl < 4; ++tl) {
    accr[tl] = (floatx4){0.f, 0.f, 0.f, 0.f};
    acci[tl] = (floatx4){0.f, 0.f, 0.f, 0.f};
  }

  auto stageA = [&](int c, int buf) {
    _Float16* L = lds[buf];
    const _Float16* xc = xb + mlo + c * 32;
    dma16(xc + asrc0, L + wave * 512);          // rows  0..31, dest u*16B
    dma16(xc + asrc1, L + 2048 + wave * 512);   // rows 32..63
  };

  half8 U0{}, U1{}, U2{}, U3{}, V0{}, V1{}, V2{}, V3{};

  // chunk ch is computed at parity p(ch)=((ch-slo)/2)&1: p=0 -> U, p=1 -> V.
  // Prefetch of ch happens one iteration earlier into the matching buffer.
  // All slice lengths give an even number of 2-chunk steps (24/20/12).
  stageA(slo, 0);
  if (gvalid && cw0 == slo) BLD(U, slo);
  int buf = 0;
  int c = slo;
  #pragma unroll 1
  for (; c + 2 < shi; c += 4) {
    // phase 0: chunk pair c in U; prefetch c+2 -> V
    __syncthreads();                     // drains A-DMA (and last B loads)
    stageA(c + 2, buf ^ 1);
    if (gvalid && c + 2 >= cw0) BLD(V, c + 2);
    __builtin_amdgcn_sched_barrier(0);   // pin B prefetch before MFMAs
    if (gvalid && c >= cw0) MMC(U, buf);
    buf ^= 1;
    // phase 1: chunk pair c+2 in V; prefetch c+4 -> U
    __syncthreads();
    if (c + 4 < shi) stageA(c + 4, buf ^ 1);
    if (gvalid && c + 4 < shi && c + 4 >= cw0) BLD(U, c + 4);
    __builtin_amdgcn_sched_barrier(0);
    if (gvalid && c + 2 >= cw0) MMC(V, buf);
    buf ^= 1;
  }

  if (PARTIAL) {
    // exclusive-region f16 partial stores: 4 x 16B per lane, no RMW
    _Float16* pw = part +
        (((size_t)sx * kFBB + blockIdx.x) * 4 + wave) * 2048 + lane * 32;
    #pragma unroll
    for (int tl = 0; tl < 4; ++tl) {
      half8 p;
      #pragma unroll
      for (int r = 0; r < 4; ++r) {
        p[r * 2]     = (_Float16)accr[tl][r];
        p[r * 2 + 1] = (_Float16)acci[tl][r];
      }
      *(half8*)(pw + tl * 8) = p;
    }
  } else {
    // guarded agent-atomic split-K combine
    const int bin = g16 * 16 + mm;
    if (gvalid && bin < kBins) {
      #pragma unroll
      for (int tl = 0; tl < 4; ++tl) {
        const int tb = fbase + tl * 16 + q * 4;
        #pragma unroll
        for (int r = 0; r < 4; ++r) {
          const int t = tb + r;
          if (t < kT) {
            const size_t o = (((size_t)b * kT + t) * kBins + bin) * 2;
            atomAddF(&accb[o],     accr[tl][r] * kKScaleInv);
            atomAddF(&accb[o + 1], acci[tl][r] * kKScaleInv);
          }
        }
      }
    }
  }
}
#undef BLD
#undef MMC

// ---- path P final: sum slice partials -> magnitude -> out ----
__global__ __launch_bounds__(256) void cqt_mag_part(
    const _Float16* __restrict__ part, float* __restrict__ out,
    const JobsC jt) {
  const int fbb = blockIdx.x;          // 0..43
  const int fb = fbb >> 2;
  const int b  = fbb & 3;
  const int wave = threadIdx.x >> 6;
  const int lane = threadIdx.x & 63;
  const int g16 = blockIdx.y * 4 + wave;
  if (g16 >= kG16) return;
  const int mac = g16 >> 2;
  const int w   = g16 & 3;
  const int mm = lane & 15;
  const int q  = lane >> 4;

  float a[32];
  #pragma unroll
  for (int i = 0; i < 32; ++i) a[i] = 0.f;
  const int s0 = jt.sbeg[mac];
  const int s1 = s0 + jt.scnt[mac];
  #pragma unroll 1
  for (int s = s0; s < s1; ++s) {
    const _Float16* p = part +
        (((size_t)s * kFBB + fbb) * 4 + w) * 2048 + lane * 32;
    #pragma unroll
    for (int tl = 0; tl < 4; ++tl) {
      const half8 v = *(const half8*)(p + tl * 8);
      #pragma unroll
      for (int j = 0; j < 8; ++j) a[tl * 8 + j] += (float)v[j];
    }
  }
  const int k = g16 * 16 + mm;
  if (k >= kBins) return;
  #pragma unroll
  for (int tl = 0; tl < 4; ++tl) {
    #pragma unroll
    for (int r = 0; r < 4; ++r) {
      const int t = fb * 64 + tl * 16 + q * 4 + r;
      if (t < kT) {
        const float re = a[tl * 8 + r * 2];
        const float im = a[tl * 8 + r * 2 + 1];
        out[((size_t)b * kT + t) * kBins + k] =
            sqrtf(re * re + im * im) * kKScaleInv;
      }
    }
  }
}

// ---- path A final: magnitude, 4 outputs/thread ----
__global__ __launch_bounds__(256) void cqt_mag4(
    const float* __restrict__ accb, float* __restrict__ out) {
  const int gid = (blockIdx.x * 256 + threadIdx.x) * 4;
  if (gid >= kB * kT * kBins) return;
  const floatx4 v0 = *(const floatx4*)&accb[gid * 2];
  const floatx4 v1 = *(const floatx4*)&accb[gid * 2 + 4];
  floatx4 o;
  o[0] = sqrtf(v0[0] * v0[0] + v0[1] * v0[1]);
  o[1] = sqrtf(v0[2] * v0[2] + v0[3] * v0[3]);
  o[2] = sqrtf(v1[0] * v1[0] + v1[1] * v1[1]);
  o[3] = sqrtf(v1[2] * v1[2] + v1[3] * v1[3]);
  *(floatx4*)&out[gid] = o;
}

// ---- path B final: magnitude (layout-parametric) ----
__global__ __launch_bounds__(256) void cqt_mag_final(
    const float* __restrict__ accb, float* __restrict__ out,
    const int tp, const int kp) {
  int gid = blockIdx.x * 256 + threadIdx.x;
  if (gid >= kB * kT * kBins) return;
  const int k = gid % kBins;
  const int r = gid / kBins;
  const int t = r % kT;
  const int b = r / kT;
  const float2 v = ((const float2*)accb)[((size_t)b * tp + t) * kp + k];
  out[gid] = sqrtf(v.x * v.x + v.y * v.y);
}

// ================= path B: round-3 LDS-staging MFMA (verified) =============
__global__ __launch_bounds__(256) void prep_x_kernel(
    const float* __restrict__ x, _Float16* __restrict__ xp,
    const int pad, const int xps) {
  const int halfx = xps >> 1;
  int gid = blockIdx.x * 256 + threadIdx.x;
  if (gid >= kB * halfx) return;
  const int b = gid / halfx;
  const int i = (gid - b * halfx) * 2;
  float v0 = 0.f, v1 = 0.f;
  if (i     >= pad && i     < pad + kS) v0 = x[(size_t)b * kS + (i - pad)];
  if (i + 1 >= pad && i + 1 < pad + kS) v1 = x[(size_t)b * kS + (i + 1 - pad)];
  half2v h; h.x = (_Float16)v0; h.y = (_Float16)v1;
  *(half2v*)&xp[(size_t)b * xps + i] = h;
}

__global__ __launch_bounds__(256) void cqt_mfma_kernel(
    const float* __restrict__ kr, const float* __restrict__ ki,
    const _Float16* __restrict__ xp, float* __restrict__ accb,
    const int nmax, const int xps, const Jobs jt) {
  __shared__ _Float16 Bs[2][16][264];
  const int jb = blockIdx.x;
  const int k0   = jt.k0[jb];
  const int n_lo = jt.lo[jb];
  const int n_hi = jt.hi[jb];
  const int b  = blockIdx.z;
  const int fb = blockIdx.y;
  const int tid  = threadIdx.x;
  const int lane = tid & 63;
  const int wave = tid >> 6;
  const int m = lane & 15;
  const int q = lane >> 4;
  const int sbin = tid >> 4;
  const int scol = tid & 15;
  const int gbin = k0 + sbin;
  const bool binok = (gbin < kBins);
  const float* rowr = kr + (size_t)gbin * nmax;
  const float* rowi = ki + (size_t)gbin * nmax;
  const int fbase = fb * 256 + wave * 64;
  const _Float16* ax =
      xp + (size_t)b * xps + (size_t)(fbase + m) * kHop + q * 8;
  floatx4 accr[4], acci[4];
  #pragma unroll
  for (int tl = 0; tl < 4; ++tl) {
    accr[tl] = (floatx4){0.f, 0.f, 0.f, 0.f};
    acci[tl] = (floatx4){0.f, 0.f, 0.f, 0.f};
  }
  for (int n0r = n_lo; n0r < n_hi; n0r += 256) {
    __syncthreads();
    #pragma unroll
    for (int c = 0; c < 16; ++c) {
      const int col = n0r + scol + c * 16;
      const bool ok = binok && (col < nmax);
      const float vr = ok ? rowr[col] : 0.f;
      const float vi = ok ? rowi[col] : 0.f;
      Bs[0][sbin][scol + c * 16] = (_Float16)(vr * kKScale);
      Bs[1][sbin][scol + c * 16] = (_Float16)(vi * kKScale);
    }
    __syncthreads();
    const _Float16* axr = ax + n0r;
    #pragma unroll
    for (int c = 0; c < 8; ++c) {
      const int ko = c * 32 + q * 8;
      const half8 br = *(const half8*)&Bs[0][m][ko];
      const half8 bi = *(const half8*)&Bs[1][m][ko];
      #pragma unroll
      for (int tl = 0; tl < 4; ++tl) {
        const half8 a = *(const half8*)(axr + tl * 16 * kHop + c * 32);
        accr[tl] = __builtin_amdgcn_mfma_f32_16x16x32_f16(a, br, accr[tl], 0, 0, 0);
        acci[tl] = __builtin_amdgcn_mfma_f32_16x16x32_f16(a, bi, acci[tl], 0, 0, 0);
      }
    }
  }
  #pragma unroll
  for (int tl = 0; tl < 4; ++tl) {
    #pragma unroll
    for (int rr = 0; rr < 4; ++rr) {
      const int t = fbase + tl * 16 + q * 4 + rr;
      const size_t o = (((size_t)b * kTPadB + t) * kBinPadB + (k0 + m)) * 2;
      atomAddF(&accb[o],     accr[tl][rr] * kKScaleInv);
      atomAddF(&accb[o + 1], acci[tl][rr] * kKScaleInv);
    }
  }
}

// ================= path C: verified fp32 kernel (round 2) ==================
namespace fb32 {
constexpr int TT = 8;
constexpr int KG = 4;
constexpr int kTTiles  = (kT + TT - 1) / TT;
constexpr int kKGroups = kBins / KG;
constexpr int kWaves   = kB * kTTiles * kKGroups;
}

__global__ __launch_bounds__(256) void cqt_mag_kernel(
    const float* __restrict__ x,
    const float* __restrict__ kr,
    const float* __restrict__ ki,
    float* __restrict__ out,
    const int nmax, const int pad) {
  using namespace fb32;
  const int wave = (blockIdx.x << 2) + (threadIdx.x >> 6);
  const int lane = threadIdx.x & 63;
  if (wave >= kWaves) return;
  const int kg    = wave / (kB * kTTiles);
  const int rem   = wave - kg * (kB * kTTiles);
  const int b     = rem / kTTiles;
  const int ttile = rem - b * kTTiles;
  const int k0 = kg * KG;
  const int t0 = ttile * TT;
  const double Q  = 1.0 / (exp2(1.0 / 24.0) - 1.0);
  const double f0 = 32.7 * exp2((double)k0 / 24.0);
  int N = (int)ceil(Q * (double)kSR / f0) + 8;
  int full_start = nmax - N;
  if (full_start < 0) full_start = 0;
  int tbase[TT], lo[TT], t_last;
  { int t = t0 + TT - 1; if (t > kT - 1) t = kT - 1; t_last = t; }
  #pragma unroll
  for (int tt = 0; tt < TT; ++tt) {
    int t = t0 + tt; if (t > kT - 1) t = kT - 1;
    tbase[tt] = b * kS + t * kHop - pad;
    lo[tt]    = pad - t * kHop;
  }
  int head_start = pad - t_last * kHop;
  if (head_start < full_start) head_start = full_start;
  int safe = pad - t0 * kHop;
  if (safe < head_start) safe = head_start;
  int body_start = nmax - ((nmax - safe) & ~63);
  float accr[TT][KG], acci[TT][KG];
  #pragma unroll
  for (int tt = 0; tt < TT; ++tt)
    #pragma unroll
    for (int kk = 0; kk < KG; ++kk) { accr[tt][kk] = 0.f; acci[tt][kk] = 0.f; }
  for (int n = body_start - 64; n > head_start - 64; n -= 64) {
    const int nn = n + lane;
    const bool kok = (nn >= 0);
    float krv[KG], kiv[KG];
    #pragma unroll
    for (int kk = 0; kk < KG; ++kk) {
      krv[kk] = kok ? kr[(k0 + kk) * nmax + nn] : 0.f;
      kiv[kk] = kok ? ki[(k0 + kk) * nmax + nn] : 0.f;
    }
    float a[TT];
    #pragma unroll
    for (int tt = 0; tt < TT; ++tt)
      a[tt] = (nn >= lo[tt]) ? x[tbase[tt] + nn] : 0.f;
    #pragma unroll
    for (int tt = 0; tt < TT; ++tt)
      #pragma unroll
      for (int kk = 0; kk < KG; ++kk) {
        accr[tt][kk] = fmaf(a[tt], krv[kk], accr[tt][kk]);
        acci[tt][kk] = fmaf(a[tt], kiv[kk], acci[tt][kk]);
      }
  }
  for (int n = body_start; n < nmax; n += 64) {
    const int nn = n + lane;
    float krv[KG], kiv[KG];
    #pragma unroll
    for (int kk = 0; kk < KG; ++kk) {
      krv[kk] = kr[(k0 + kk) * nmax + nn];
      kiv[kk] = ki[(k0 + kk) * nmax + nn];
    }
    float a[TT];
    #pragma unroll
    for (int tt = 0; tt < TT; ++tt)
      a[tt] = x[tbase[tt] + nn];
    #pragma unroll
    for (int tt = 0; tt < TT; ++tt)
      #pragma unroll
      for (int kk = 0; kk < KG; ++kk) {
        accr[tt][kk] = fmaf(a[tt], krv[kk], accr[tt][kk]);
        acci[tt][kk] = fmaf(a[tt], kiv[kk], acci[tt][kk]);
      }
  }
  #pragma unroll
  for (int tt = 0; tt < TT; ++tt) {
    #pragma unroll
    for (int kk = 0; kk < KG; ++kk) {
      float r = accr[tt][kk];
      float i = acci[tt][kk];
      #pragma unroll
      for (int s = 32; s > 0; s >>= 1) {
        r += __shfl_xor(r, s, 64);
        i += __shfl_xor(i, s, 64);
      }
      if (lane == 0) {
        const int t = t0 + tt;
        if (t < kT)
          out[(b * kT + t) * kBins + (k0 + kk)] = sqrtf(r * r + i * i);
      }
    }
  }
}
// ============================================================================

extern "C" void kernel_launch(void* const* d_in, const int* in_sizes, int n_in,
                              void* d_out, int out_size, void* d_ws, size_t ws_size,
                              hipStream_t stream) {
  const float* x  = (const float*)d_in[0];   // [4, 1, 352768]
  const float* kr = (const float*)d_in[1];   // [168, nmax]
  const float* ki = (const float*)d_in[2];   // [168, nmax]
  float* out = (float*)d_out;                // [4, 1, 689, 168]

  const int nmax = in_sizes[1] / kBins;      // 23013 (runtime truth)
  const int pad  = nmax - kHop;

  const int kcap = ((nmax + 255) / 256) * 256;   // 23040
  const double Q = 1.0 / (exp2(1.0 / 24.0) - 1.0);

  // ---- path P/A tables ----
  JobsC jc;
  int tot = 0;
  for (int g = 0; g < kG16; ++g) {
    const double f0 = 32.7 * exp2((double)(16 * g) / 24.0);
    const int N = (int)ceil(Q * (double)kSR / f0) + 8;
    int lo = nmax - N;
    if (lo < 0) lo = 0;
    lo &= ~255;
    jc.lo16[g] = lo;
    jc.cb16[g] = tot;
    tot += (kcap - lo) / 32;
  }
  jc.totch = tot;                        // ~1984 chunks
  // ns=19 slice table (48-chunk slices -> 15/3/1; lengths give an even
  // number of 2-chunk steps, required by the main loop's 2x unroll)
  int ns = 0;
  for (int m = 0; m < 3; ++m) {
    jc.mlo[m] = jc.lo16[4 * m];
    jc.sbeg[m] = ns;
    const int C = (kcap - jc.mlo[m]) / 32;       // 720 / 120 / 24
    const int nsl = (C + 47) / 48;               // 15 / 3 / 1
    const int len = ((C + nsl - 1) / nsl + 1) & ~1;
    for (int s = 0; s < nsl && ns < 24; ++s) {
      const int lo = s * len;
      if (lo >= C) break;
      int hi = lo + len;
      if (hi > C) hi = C;
      jc.sm[ns] = m; jc.slo[ns] = lo; jc.shi[ns] = hi;
      ++ns;
    }
    jc.scnt[m] = ns - jc.sbeg[m];
  }
  jc.ns = ns;                            // 19 expected

  // ---- shared ws pieces ----
  const int xpsA = (kT - 1) * kHop + kcap + 256;           // 375,552 (%8==0)
  const size_t xpA_bytes = (size_t)kB * xpsA * sizeof(_Float16);
  const size_t bpA_bytes = (size_t)tot * 2048;

  // path P layout: xp | part(f16) | bp
  const size_t partP_off   = (xpA_bytes + 511) & ~(size_t)511;
  const size_t partP_bytes = (size_t)ns * kFBB * 4 * 2048 * sizeof(_Float16);
  const size_t bpP_off     = (partP_off + partP_bytes + 511) & ~(size_t)511;
  const size_t ws_P = bpP_off + bpA_bytes;                 // ~20.8 MB

  // path A layout: xp | acc(f32) | bp
  const size_t accA_off  = (xpA_bytes + 511) & ~(size_t)511;
  const size_t accA_bytes = (size_t)kAcc * sizeof(float);
  const size_t bpA_off   = (accA_off + accA_bytes + 511) & ~(size_t)511;
  const size_t ws_A = bpA_off + bpA_bytes;                 // ~10.8 MB

  // path B layout
  const int xpsB = (kTPadB - 1) * kHop + kcap + 256;
  const size_t xpB_bytes = (size_t)kB * xpsB * sizeof(_Float16);
  const size_t accB_off  = (xpB_bytes + 511) & ~(size_t)511;
  const size_t accB_bytes = (size_t)kAccB * sizeof(float);
  const size_t ws_B = accB_off + accB_bytes;

  const int nbx = (kB * (xpsA / 8) + 255) / 256;   // audio blocks (8 el/thr)
  const int nbp = (tot + 3) / 4;                   // bpack blocks (4 chunks ea)

  if (ws_size >= ws_P) {
    // ---- path P: partial-store split-K, no atomics ----
    _Float16* xp   = (_Float16*)d_ws;
    _Float16* part = (_Float16*)((char*)d_ws + partP_off);
    _Float16* bp   = (_Float16*)((char*)d_ws + bpP_off);

    prep_fused<<<nbx + nbp, 256, 0, stream>>>(
        x, kr, ki, xp, bp, (float*)part /*unused*/, pad, xpsA, nmax,
        nbx, nbp, jc);
    {
      dim3 grid(kFBB, ns);
      cqt_mfma_t<true><<<grid, 256, 0, stream>>>(
          bp, xp, nullptr, part, xpsA, jc);
    }
    {
      dim3 grid(kFBB, 3);    // 11 g16 waves per (fb,b) in 3 4-wave WGs
      cqt_mag_part<<<grid, 256, 0, stream>>>(part, out, jc);
    }
    return;
  }

  if (ws_size >= ws_A) {
    // ---- path A: atomic split-K ----
    _Float16* xp = (_Float16*)d_ws;
    float* accb  = (float*)((char*)d_ws + accA_off);
    _Float16* bp = (_Float16*)((char*)d_ws + bpA_off);

    const int nba = (kAcc / 4 + 255) / 256;
    prep_fused<<<nbx + nbp + nba, 256, 0, stream>>>(
        x, kr, ki, xp, bp, accb, pad, xpsA, nmax, nbx, nbp, jc);
    {
      dim3 grid(kFBB, ns);
      cqt_mfma_t<false><<<grid, 256, 0, stream>>>(
          bp, xp, accb, nullptr, xpsA, jc);
    }
    {
      const int total = kB * kT * kBins;
      cqt_mag4<<<(total / 4 + 255) / 256, 256, 0, stream>>>(accb, out);
    }
    return;
  }

  if (ws_size >= ws_B) {
    // ---- path B (round-3, verified ~224us) ----
    _Float16* xp = (_Float16*)d_ws;
    float* accb  = (float*)((char*)d_ws + accB_off);
    Jobs jt;
    int nj = 0;
    for (int g = 0; g < 11; ++g) {
      const int gk0 = 16 * g;
      const double f0 = 32.7 * exp2((double)gk0 / 24.0);
      const int N = (int)ceil(Q * (double)kSR / f0) + 8;
      int lo = nmax - N;
      if (lo < 0) lo = 0;
      lo = (lo / 2048) * 2048;
      for (int s = lo; s < kcap && nj < 48; s += 2048) {
        jt.k0[nj] = gk0;
        jt.lo[nj] = s;
        jt.hi[nj] = (s + 2048 < kcap) ? s + 2048 : kcap;
        ++nj;
      }
    }
    jt.n = nj;
    hipMemsetAsync(accb, 0, accB_bytes, stream);
    {
      const int total = kB * (xpsB / 2);
      prep_x_kernel<<<(total + 255) / 256, 256, 0, stream>>>(x, xp, pad, xpsB);
    }
    {
      dim3 grid(nj, kTPadB / 256, kB);
      cqt_mfma_kernel<<<grid, 256, 0, stream>>>(kr, ki, xp, accb, nmax, xpsB, jt);
    }
    {
      const int total = kB * kT * kBins;
      cqt_mag_final<<<(total + 255) / 256, 256, 0, stream>>>(
          accb, out, kTPadB, kBinPadB);
    }
    return;
  }

  // ---- path C: fp32 fallback ----
  {
    const int blocks = fb32::kWaves / 4;
    cqt_mag_kernel<<<blocks, 256, 0, stream>>>(x, kr, ki, out, nmax, pad);
  }
}